// Round 1
// baseline (3848.973 us; speedup 1.0000x reference)
//
#include <hip/hip_runtime.h>
#include <hip/hip_bf16.h>

typedef __hip_bfloat16 bf16;
typedef __attribute__((ext_vector_type(8))) unsigned short ushort8v;

#define NTOK 4096
#define DMODEL 1024
#define NHEADS 16
#define HD 64
#define DC 128
#define DFF2 4096
#define NEXP 8
#define LSEQ 1024
#define NBATCH 4
#define RMS_EPS 1.1920928955078125e-07f

__device__ __forceinline__ float bf2f(unsigned short u) {
  return __uint_as_float(((unsigned int)u) << 16);
}

// ---------------------------------------------------------------- rmsnorm
__global__ __launch_bounds__(256)
void rmsnorm_kernel(const float* __restrict__ x, const float* __restrict__ w,
                    float* __restrict__ o) {
  int t = blockIdx.x;
  int tid = threadIdx.x;
  const float4* xr = (const float4*)(x + (size_t)t * DMODEL);
  float4 v = xr[tid];
  float ss = v.x * v.x + v.y * v.y + v.z * v.z + v.w * v.w;
#pragma unroll
  for (int off = 32; off > 0; off >>= 1) ss += __shfl_xor(ss, off);
  __shared__ float red[4];
  int wid = tid >> 6, lane = tid & 63;
  if (lane == 0) red[wid] = ss;
  __syncthreads();
  float tot = red[0] + red[1] + red[2] + red[3];
  float scale = rsqrtf(tot * (1.0f / DMODEL) + RMS_EPS);
  float4 wv = ((const float4*)w)[tid];
  float4 ov;
  ov.x = v.x * scale * wv.x;
  ov.y = v.y * scale * wv.y;
  ov.z = v.z * scale * wv.z;
  ov.w = v.w * scale * wv.w;
  ((float4*)(o + (size_t)t * DMODEL))[tid] = ov;
}

// ---------------------------------------------------------------- GEMM  C[M,N] = A[M,K] @ W[N,K]^T
// MODE 0: f32 A, f32 store
// MODE 1: f32 A, f32 store + addend (residual x)
// MODE 2: grouped MoE FFN1: A rows gathered via tok2e (hn), silu -> bf16 store to hmid
// MODE 3: grouped MoE FFN2: A = bf16 hmid (contiguous per expert), store f32 scatter rows to y
template <int MODE>
__global__ __launch_bounds__(256)
void gemm_bt(const float* __restrict__ Af, const bf16* __restrict__ Ab,
             const float* __restrict__ W_, float* __restrict__ Cf,
             bf16* __restrict__ Cb, const float* __restrict__ addend,
             const int* __restrict__ tok2e, const int* __restrict__ ebase,
             const int* __restrict__ icnt, int M, int N, int K) {
  constexpr int BM = 128, BN = 128, BK = 16;
  __shared__ float As[BK][BM + 4];
  __shared__ float Bs[BK][BN + 4];
  int base = 0, cnt = M;
  const float* Wp = W_;
  if (MODE == 2 || MODE == 3) {
    int e = blockIdx.z;
    base = ebase[e];
    cnt = icnt[e];
    Wp = W_ + (size_t)e * (size_t)N * (size_t)K;
  }
  int row0 = blockIdx.y * BM;
  if (row0 >= cnt) return;
  int col0 = blockIdx.x * BN;
  int tid = threadIdx.x;

  // W load setup (always f32): rows tid>>2 and tid>>2+64, 4 k each
  int wrl = tid >> 2;
  int wkq = (tid & 3) * 4;
  const float* wptr0 = Wp + (size_t)(col0 + wrl) * K + wkq;
  const float* wptr1 = wptr0 + (size_t)64 * K;

  // A load setup
  const float* aptr0 = nullptr;
  const float* aptr1 = nullptr;
  const bf16* abptr = nullptr;
  if (MODE == 3) {
    int r = tid >> 1;
    int kq = (tid & 1) * 8;
    if (row0 + r < cnt) abptr = Ab + (size_t)(base + row0 + r) * K + kq;
  } else {
    int r0 = tid >> 2, r1 = (tid >> 2) + 64;
    int kq = (tid & 3) * 4;
    if (MODE == 2) {
      if (row0 + r0 < cnt) aptr0 = Af + (size_t)(tok2e[base + row0 + r0] >> 1) * K + kq;
      if (row0 + r1 < cnt) aptr1 = Af + (size_t)(tok2e[base + row0 + r1] >> 1) * K + kq;
    } else {
      aptr0 = Af + (size_t)(row0 + r0) * K + kq;
      aptr1 = Af + (size_t)(row0 + r1) * K + kq;
    }
  }

  float acc[8][8] = {};
  int ty = tid >> 4, tx = tid & 15;

  for (int k0 = 0; k0 < K; k0 += BK) {
    if (MODE == 3) {
      int r = tid >> 1;
      int kq = (tid & 1) * 8;
      if (abptr) {
        ushort8v u8 = *(const ushort8v*)(abptr + k0);
#pragma unroll
        for (int j = 0; j < 8; ++j) As[kq + j][r] = bf2f(u8[j]);
      } else {
#pragma unroll
        for (int j = 0; j < 8; ++j) As[kq + j][r] = 0.f;
      }
    } else {
      int r0 = tid >> 2, r1 = (tid >> 2) + 64;
      int kq = (tid & 3) * 4;
      float4 a0 = aptr0 ? *(const float4*)(aptr0 + k0) : make_float4(0.f, 0.f, 0.f, 0.f);
      float4 a1 = aptr1 ? *(const float4*)(aptr1 + k0) : make_float4(0.f, 0.f, 0.f, 0.f);
      As[kq + 0][r0] = a0.x; As[kq + 1][r0] = a0.y; As[kq + 2][r0] = a0.z; As[kq + 3][r0] = a0.w;
      As[kq + 0][r1] = a1.x; As[kq + 1][r1] = a1.y; As[kq + 2][r1] = a1.z; As[kq + 3][r1] = a1.w;
    }
    {
      float4 b0 = *(const float4*)(wptr0 + k0);
      float4 b1 = *(const float4*)(wptr1 + k0);
      Bs[wkq + 0][wrl] = b0.x; Bs[wkq + 1][wrl] = b0.y; Bs[wkq + 2][wrl] = b0.z; Bs[wkq + 3][wrl] = b0.w;
      Bs[wkq + 0][wrl + 64] = b1.x; Bs[wkq + 1][wrl + 64] = b1.y; Bs[wkq + 2][wrl + 64] = b1.z; Bs[wkq + 3][wrl + 64] = b1.w;
    }
    __syncthreads();
#pragma unroll
    for (int kk = 0; kk < BK; ++kk) {
      float4 a0 = *(const float4*)&As[kk][ty * 8];
      float4 a1 = *(const float4*)&As[kk][ty * 8 + 4];
      float4 b0 = *(const float4*)&Bs[kk][tx * 8];
      float4 b1 = *(const float4*)&Bs[kk][tx * 8 + 4];
      float av[8] = {a0.x, a0.y, a0.z, a0.w, a1.x, a1.y, a1.z, a1.w};
      float bv[8] = {b0.x, b0.y, b0.z, b0.w, b1.x, b1.y, b1.z, b1.w};
#pragma unroll
      for (int i = 0; i < 8; ++i)
#pragma unroll
        for (int j = 0; j < 8; ++j) acc[i][j] = fmaf(av[i], bv[j], acc[i][j]);
    }
    __syncthreads();
  }

  // epilogue
  if (MODE == 0 || MODE == 1) {
#pragma unroll
    for (int i = 0; i < 8; ++i) {
      int grow = row0 + ty * 8 + i;
      size_t cidx = (size_t)grow * N + col0 + tx * 8;
      float4 o0 = make_float4(acc[i][0], acc[i][1], acc[i][2], acc[i][3]);
      float4 o1 = make_float4(acc[i][4], acc[i][5], acc[i][6], acc[i][7]);
      if (MODE == 1) {
        float4 d0 = *(const float4*)(addend + cidx);
        float4 d1 = *(const float4*)(addend + cidx + 4);
        o0.x += d0.x; o0.y += d0.y; o0.z += d0.z; o0.w += d0.w;
        o1.x += d1.x; o1.y += d1.y; o1.z += d1.z; o1.w += d1.w;
      }
      *(float4*)(Cf + cidx) = o0;
      *(float4*)(Cf + cidx + 4) = o1;
    }
  } else if (MODE == 2) {
#pragma unroll
    for (int i = 0; i < 8; ++i) {
      int rr = ty * 8 + i;
      if (row0 + rr < cnt) {
        bf16* crow = Cb + (size_t)(base + row0 + rr) * N + col0 + tx * 8;
#pragma unroll
        for (int j = 0; j < 8; ++j) {
          float vv = acc[i][j];
          float s = vv / (1.f + __expf(-vv));
          crow[j] = __float2bfloat16(s);
        }
      }
    }
  } else {  // MODE 3
#pragma unroll
    for (int i = 0; i < 8; ++i) {
      int rr = ty * 8 + i;
      if (row0 + rr < cnt) {
        int t2 = tok2e[base + row0 + rr];
        float* crow = Cf + (size_t)t2 * N + col0 + tx * 8;
#pragma unroll
        for (int j = 0; j < 8; ++j) crow[j] = acc[i][j];
      }
    }
  }
}

// ---------------------------------------------------------------- rope (cos-only, per reference) + ksum = k_c + roped k_r ; q *= 0.125
__global__ __launch_bounds__(256)
void rope_kernel(float* __restrict__ q, float* __restrict__ k,
                 const float* __restrict__ kc, const float* __restrict__ tsq,
                 const float* __restrict__ tskv) {
  int t = blockIdx.x;
  int tid = threadIdx.x;
  __shared__ float cq[32], ck[32];
  if (tid < 32) {
    float fr = __expf(-(float)(2 * tid) * (1.0f / HD) * 9.210340371976184f);  // ln(10000)
    cq[tid] = cosf(tsq[t] * fr);
    ck[tid] = cosf(tskv[t] * fr);
  }
  __syncthreads();
  size_t rb = (size_t)t * DMODEL;
  for (int p = tid; p < 512; p += 256) {
    int hh = p >> 5, d = p & 31;
    int c1 = hh * 64 + d, c2 = c1 + 32;
    float cqd = cq[d], ckd = ck[d];
    float q1 = q[rb + c1], q2 = q[rb + c2];
    q[rb + c1] = (q1 * cqd - q2 * ckd) * 0.125f;
    q[rb + c2] = (q2 * cqd + q1 * ckd) * 0.125f;
    float k1 = k[rb + c1], k2 = k[rb + c2];
    k[rb + c1] = (k1 * cqd - k2 * ckd) + kc[rb + c1];
    k[rb + c2] = (k2 * cqd + k1 * ckd) + kc[rb + c2];
  }
}

// ---------------------------------------------------------------- fused attention: 4 q-rows per block, full softmax over 1024 keys
__global__ __launch_bounds__(256)
void attn_kernel(const float* __restrict__ q, const float* __restrict__ k,
                 const float* __restrict__ v, float* __restrict__ out) {
  __shared__ float sc[4][LSEQ];
  __shared__ float qs[4][HD];
  __shared__ float4 klds4[64 * 16];
  __shared__ float red[16][HD];
  __shared__ float sinv[4];
  int b = blockIdx.z, h = blockIdx.y;
  int lq0 = blockIdx.x * 4;
  int tid = threadIdx.x;
  int lane = tid & 63, wid = tid >> 6;
  size_t basebh = (size_t)b * LSEQ * DMODEL + h * HD;

  qs[wid][lane] = q[basebh + (size_t)(lq0 + wid) * DMODEL + lane];
  __syncthreads();

  float4 qreg[16];
#pragma unroll
  for (int c = 0; c < 16; ++c) qreg[c] = *(const float4*)&qs[wid][c * 4];

  // scores: tile over 64 keys, XOR-swizzled LDS tile (bank-conflict-free b128 reads)
  for (int kt = 0; kt < 16; ++kt) {
    int lr = tid >> 2;
    int c0 = (tid & 3) * 4;
    const float4* src = (const float4*)(k + basebh + (size_t)(kt * 64 + lr) * DMODEL) + c0;
#pragma unroll
    for (int i = 0; i < 4; ++i) klds4[lr * 16 + ((c0 + i) ^ (lr & 15))] = src[i];
    __syncthreads();
    float s = 0.f;
#pragma unroll
    for (int c = 0; c < 16; ++c) {
      float4 kv4 = klds4[lane * 16 + (c ^ (lane & 15))];
      float4 qv4 = qreg[c];
      s += qv4.x * kv4.x + qv4.y * kv4.y + qv4.z * kv4.z + qv4.w * kv4.w;
    }
    sc[wid][kt * 64 + lane] = s;
    __syncthreads();
  }

  // softmax: wave wid owns q-row wid
  {
    float m = -1e30f;
    for (int kk = lane; kk < LSEQ; kk += 64) m = fmaxf(m, sc[wid][kk]);
#pragma unroll
    for (int off = 32; off > 0; off >>= 1) m = fmaxf(m, __shfl_xor(m, off));
    float sum = 0.f;
    for (int kk = lane; kk < LSEQ; kk += 64) {
      float p = __expf(sc[wid][kk] - m);
      sc[wid][kk] = p;
      sum += p;
    }
#pragma unroll
    for (int off = 32; off > 0; off >>= 1) sum += __shfl_xor(sum, off);
    if (lane == 0) sinv[wid] = 1.0f / sum;
  }
  __syncthreads();

  // PV: wave wid covers key range [wid*256, wid*256+256), lane = head dim
  {
    float a0 = 0.f, a1 = 0.f, a2 = 0.f, a3 = 0.f;
    const float* vb = v + basebh + lane;
    int kbeg = wid * 256;
    for (int kk = kbeg; kk < kbeg + 256; kk += 4) {
      float4 p0 = *(const float4*)&sc[0][kk];
      float4 p1 = *(const float4*)&sc[1][kk];
      float4 p2 = *(const float4*)&sc[2][kk];
      float4 p3 = *(const float4*)&sc[3][kk];
      float v0 = vb[(size_t)(kk + 0) * DMODEL];
      float v1 = vb[(size_t)(kk + 1) * DMODEL];
      float v2 = vb[(size_t)(kk + 2) * DMODEL];
      float v3 = vb[(size_t)(kk + 3) * DMODEL];
      a0 += p0.x * v0 + p0.y * v1 + p0.z * v2 + p0.w * v3;
      a1 += p1.x * v0 + p1.y * v1 + p1.z * v2 + p1.w * v3;
      a2 += p2.x * v0 + p2.y * v1 + p2.z * v2 + p2.w * v3;
      a3 += p3.x * v0 + p3.y * v1 + p3.z * v2 + p3.w * v3;
    }
    red[wid * 4 + 0][lane] = a0;
    red[wid * 4 + 1][lane] = a1;
    red[wid * 4 + 2][lane] = a2;
    red[wid * 4 + 3][lane] = a3;
  }
  __syncthreads();
  {
    float o = (red[0 * 4 + wid][lane] + red[1 * 4 + wid][lane] +
               red[2 * 4 + wid][lane] + red[3 * 4 + wid][lane]) * sinv[wid];
    out[basebh + (size_t)(lq0 + wid) * DMODEL + lane] = o;
  }
}

// ---------------------------------------------------------------- gating (exact f32), top-2, counts
__global__ __launch_bounds__(256)
void gate_kernel(const float* __restrict__ hn, const float* __restrict__ gw,
                 const float* __restrict__ bias, int* __restrict__ ti,
                 float* __restrict__ tw, int* __restrict__ icnt,
                 float* __restrict__ counts_out) {
  int t = blockIdx.x * 4 + (threadIdx.x >> 6);
  int lane = threadIdx.x & 63;
  const float* hrow = hn + (size_t)t * DMODEL;
  float acc[NEXP];
#pragma unroll
  for (int e = 0; e < NEXP; ++e) acc[e] = 0.f;
  for (int d = lane; d < DMODEL; d += 64) {
    float hv = hrow[d];
#pragma unroll
    for (int e = 0; e < NEXP; ++e) acc[e] += hv * gw[e * DMODEL + d];
  }
#pragma unroll
  for (int e = 0; e < NEXP; ++e)
#pragma unroll
    for (int off = 32; off > 0; off >>= 1) acc[e] += __shfl_xor(acc[e], off);
  if (lane == 0) {
    float l[NEXP], ex[NEXP];
    float mx = -1e30f;
#pragma unroll
    for (int e = 0; e < NEXP; ++e) {
      l[e] = acc[e] + bias[e];
      mx = fmaxf(mx, l[e]);
    }
#pragma unroll
    for (int e = 0; e < NEXP; ++e) ex[e] = expf(l[e] - mx);
    int i0 = 0;
    float p0 = ex[0];
#pragma unroll
    for (int e = 1; e < NEXP; ++e)
      if (ex[e] > p0) { p0 = ex[e]; i0 = e; }
    int i1 = -1;
    float p1 = -1.f;
#pragma unroll
    for (int e = 0; e < NEXP; ++e)
      if (e != i0 && ex[e] > p1) { p1 = ex[e]; i1 = e; }
    float wsum = p0 + p1;
    ti[2 * t] = i0;
    ti[2 * t + 1] = i1;
    tw[2 * t] = p0 / wsum;
    tw[2 * t + 1] = p1 / wsum;
    atomicAdd(&icnt[i0], 1);
    atomicAdd(&icnt[i1], 1);
    atomicAdd(&counts_out[i0], 1.0f);
    atomicAdd(&counts_out[i1], 1.0f);
  }
}

__global__ void init_kernel(float* __restrict__ counts_out, int* __restrict__ icnt,
                            int* __restrict__ cursor) {
  int i = threadIdx.x;
  if (i < NEXP) {
    counts_out[i] = 0.f;
    icnt[i] = 0;
    cursor[i] = 0;
  }
}

__global__ void scan_kernel(const int* __restrict__ icnt, int* __restrict__ ebase) {
  if (threadIdx.x == 0) {
    int s = 0;
    for (int e = 0; e < NEXP; ++e) {
      ebase[e] = s;
      s += icnt[e];
    }
  }
}

__global__ __launch_bounds__(256)
void scatter_kernel(const int* __restrict__ ti, const int* __restrict__ ebase,
                    int* __restrict__ cursor, int* __restrict__ tok2e) {
  int t = blockIdx.x * 256 + threadIdx.x;
#pragma unroll
  for (int s = 0; s < 2; ++s) {
    int e = ti[2 * t + s];
    int pos = atomicAdd(&cursor[e], 1);
    tok2e[ebase[e] + pos] = 2 * t + s;
  }
}

// out = x1 + tw0*y[2t] + tw1*y[2t+1]
__global__ __launch_bounds__(256)
void combine_kernel(const float* __restrict__ x1, const float* __restrict__ y,
                    const float* __restrict__ tw, float* __restrict__ out) {
  int idx = blockIdx.x * 256 + threadIdx.x;
  int t = idx >> 8, c = idx & 255;
  float w0 = tw[2 * t], w1 = tw[2 * t + 1];
  float4 a = ((const float4*)x1)[idx];
  float4 b0 = ((const float4*)y)[(size_t)(2 * t) * 256 + c];
  float4 b1 = ((const float4*)y)[(size_t)(2 * t + 1) * 256 + c];
  float4 o;
  o.x = a.x + w0 * b0.x + w1 * b1.x;
  o.y = a.y + w0 * b0.y + w1 * b1.y;
  o.z = a.z + w0 * b0.z + w1 * b1.z;
  o.w = a.w + w0 * b0.w + w1 * b1.w;
  ((float4*)out)[idx] = o;
}

// ----------------------------------------------------------------
extern "C" void kernel_launch(void* const* d_in, const int* in_sizes, int n_in,
                              void* d_out, int out_size, void* d_ws, size_t ws_size,
                              hipStream_t stream) {
  (void)in_sizes; (void)n_in; (void)ws_size;
  const float* x = (const float*)d_in[0];
  const float* tsq = (const float*)d_in[1];
  const float* tskv = (const float*)d_in[2];
  const float* attn_nw = (const float*)d_in[3];
  const float* ffn_nw = (const float*)d_in[4];
  const float* w_kv_c = (const float*)d_in[5];
  const float* w_kc_up = (const float*)d_in[6];
  const float* w_vc_up = (const float*)d_in[7];
  const float* w_qr = (const float*)d_in[8];
  const float* w_kr = (const float*)d_in[9];
  const float* w_o = (const float*)d_in[10];
  const float* gate_w = (const float*)d_in[11];
  const float* expert_bias = (const float*)d_in[12];
  const float* w1 = (const float*)d_in[13];
  const float* w2 = (const float*)d_in[14];

  float* out = (float*)d_out;
  float* counts_out = out + (out_size - NEXP);

  char* ws = (char*)d_ws;
  size_t off = 0;
  auto alloc = [&](size_t bytes) {
    char* p = ws + off;
    off += (bytes + 255) & ~(size_t)255;
    return p;
  };
  float* h   = (float*)alloc((size_t)NTOK * DMODEL * 4);   // h, later x1
  float* qb  = (float*)alloc((size_t)NTOK * DMODEL * 4);   // q_r, later hn
  float* kb  = (float*)alloc((size_t)NTOK * DMODEL * 4);   // k_r -> ksum
  float* vb  = (float*)alloc((size_t)NTOK * DMODEL * 4);   // v_c
  float* kcb = (float*)alloc((size_t)NTOK * DMODEL * 4);   // k_c, later attn_out
  float* ckv = (float*)alloc((size_t)NTOK * DC * 4);
  float* y   = (float*)alloc((size_t)NTOK * 2 * DMODEL * 4);
  float* tw  = (float*)alloc((size_t)NTOK * 2 * 4);
  int* ti    = (int*)alloc((size_t)NTOK * 2 * 4);
  int* tok2e = (int*)alloc((size_t)NTOK * 2 * 4);
  int* icnt  = (int*)alloc(NEXP * 4);
  int* ebase = (int*)alloc(NEXP * 4);
  int* cursor = (int*)alloc(NEXP * 4);
  bf16* hmid = (bf16*)alloc((size_t)NTOK * 2 * DFF2 * 2);

  init_kernel<<<1, 64, 0, stream>>>(counts_out, icnt, cursor);
  rmsnorm_kernel<<<NTOK, 256, 0, stream>>>(x, attn_nw, h);
  // projections
  gemm_bt<0><<<dim3(DC / 128, NTOK / 128), 256, 0, stream>>>(
      h, nullptr, w_kv_c, ckv, nullptr, nullptr, nullptr, nullptr, nullptr, NTOK, DC, DMODEL);
  gemm_bt<0><<<dim3(DMODEL / 128, NTOK / 128), 256, 0, stream>>>(
      h, nullptr, w_qr, qb, nullptr, nullptr, nullptr, nullptr, nullptr, NTOK, DMODEL, DMODEL);
  gemm_bt<0><<<dim3(DMODEL / 128, NTOK / 128), 256, 0, stream>>>(
      h, nullptr, w_kr, kb, nullptr, nullptr, nullptr, nullptr, nullptr, NTOK, DMODEL, DMODEL);
  gemm_bt<0><<<dim3(DMODEL / 128, NTOK / 128), 256, 0, stream>>>(
      ckv, nullptr, w_kc_up, kcb, nullptr, nullptr, nullptr, nullptr, nullptr, NTOK, DMODEL, DC);
  gemm_bt<0><<<dim3(DMODEL / 128, NTOK / 128), 256, 0, stream>>>(
      ckv, nullptr, w_vc_up, vb, nullptr, nullptr, nullptr, nullptr, nullptr, NTOK, DMODEL, DC);
  rope_kernel<<<NTOK, 256, 0, stream>>>(qb, kb, kcb, tsq, tskv);
  attn_kernel<<<dim3(LSEQ / 4, NHEADS, NBATCH), 256, 0, stream>>>(qb, kb, vb, kcb);
  gemm_bt<1><<<dim3(DMODEL / 128, NTOK / 128), 256, 0, stream>>>(
      kcb, nullptr, w_o, h, nullptr, x, nullptr, nullptr, nullptr, NTOK, DMODEL, DMODEL);
  rmsnorm_kernel<<<NTOK, 256, 0, stream>>>(h, ffn_nw, qb);  // hn
  gate_kernel<<<NTOK / 4, 256, 0, stream>>>(qb, gate_w, expert_bias, ti, tw, icnt, counts_out);
  scan_kernel<<<1, 64, 0, stream>>>(icnt, ebase);
  scatter_kernel<<<NTOK / 256, 256, 0, stream>>>(ti, ebase, cursor, tok2e);
  gemm_bt<2><<<dim3(DFF2 / 128, NTOK / 128, NEXP), 256, 0, stream>>>(
      qb, nullptr, w1, nullptr, hmid, nullptr, tok2e, ebase, icnt, NTOK, DFF2, DMODEL);
  gemm_bt<3><<<dim3(DMODEL / 128, NTOK / 128, NEXP), 256, 0, stream>>>(
      nullptr, hmid, w2, y, nullptr, nullptr, tok2e, ebase, icnt, NTOK, DMODEL, DFF2);
  combine_kernel<<<NTOK, 256, 0, stream>>>(h, y, tw, out);
}

// Round 2
// 1925.312 us; speedup vs baseline: 1.9991x; 1.9991x over previous
//
#include <hip/hip_runtime.h>
#include <hip/hip_bf16.h>

typedef __hip_bfloat16 bf16;
typedef __attribute__((ext_vector_type(8))) unsigned short ushort8v;
typedef __bf16 bf16x8 __attribute__((ext_vector_type(8)));
typedef float f32x4 __attribute__((ext_vector_type(4)));

#define NTOK 4096
#define DMODEL 1024
#define NHEADS 16
#define HD 64
#define DC 128
#define DFF2 4096
#define NEXP 8
#define LSEQ 1024
#define NBATCH 4
#define RMS_EPS 1.1920928955078125e-07f

__device__ __forceinline__ float bf2f(unsigned short u) {
  return __uint_as_float(((unsigned int)u) << 16);
}
__device__ __forceinline__ unsigned short f2bf(float f) {
  unsigned int u = __float_as_uint(f);
  unsigned int r = (u + 0x7FFF + ((u >> 16) & 1)) >> 16;
  return (unsigned short)r;
}
__device__ __forceinline__ void gload_lds16(const unsigned short* g, unsigned short* l) {
  __builtin_amdgcn_global_load_lds(
      (__attribute__((address_space(1))) void*)(const_cast<unsigned short*>(g)),
      (__attribute__((address_space(3))) void*)(l), 16, 0, 0);
}

// ---------------------------------------------------------------- rmsnorm (optional extra bf16 output)
__global__ __launch_bounds__(256)
void rmsnorm_kernel(const float* __restrict__ x, const float* __restrict__ w,
                    float* __restrict__ o, unsigned short* __restrict__ ob) {
  int t = blockIdx.x;
  int tid = threadIdx.x;
  const float4* xr = (const float4*)(x + (size_t)t * DMODEL);
  float4 v = xr[tid];
  float ss = v.x * v.x + v.y * v.y + v.z * v.z + v.w * v.w;
#pragma unroll
  for (int off = 32; off > 0; off >>= 1) ss += __shfl_xor(ss, off);
  __shared__ float red[4];
  int wid = tid >> 6, lane = tid & 63;
  if (lane == 0) red[wid] = ss;
  __syncthreads();
  float tot = red[0] + red[1] + red[2] + red[3];
  float scale = rsqrtf(tot * (1.0f / DMODEL) + RMS_EPS);
  float4 wv = ((const float4*)w)[tid];
  float4 ov;
  ov.x = v.x * scale * wv.x;
  ov.y = v.y * scale * wv.y;
  ov.z = v.z * scale * wv.z;
  ov.w = v.w * scale * wv.w;
  ((float4*)(o + (size_t)t * DMODEL))[tid] = ov;
  if (ob) {
    unsigned short* orow = ob + (size_t)t * DMODEL + tid * 4;
    orow[0] = f2bf(ov.x); orow[1] = f2bf(ov.y);
    orow[2] = f2bf(ov.z); orow[3] = f2bf(ov.w);
  }
}

// ---------------------------------------------------------------- f32 GEMM  C[M,N] = A[M,K] @ W[N,K]^T  (pre-gate exact path)
// MODE 0: f32 store ; MODE 1: f32 store + addend (residual)
template <int MODE>
__global__ __launch_bounds__(256)
void gemm_bt(const float* __restrict__ Af, const float* __restrict__ W_,
             float* __restrict__ Cf, const float* __restrict__ addend,
             int M, int N, int K) {
  constexpr int BM = 128, BN = 128, BK = 16;
  __shared__ float As[BK][BM + 4];
  __shared__ float Bs[BK][BN + 4];
  int row0 = blockIdx.y * BM;
  int col0 = blockIdx.x * BN;
  int tid = threadIdx.x;

  int wrl = tid >> 2;
  int wkq = (tid & 3) * 4;
  const float* wptr0 = W_ + (size_t)(col0 + wrl) * K + wkq;
  const float* wptr1 = wptr0 + (size_t)64 * K;
  int r0 = tid >> 2, r1 = (tid >> 2) + 64;
  int kq = (tid & 3) * 4;
  const float* aptr0 = Af + (size_t)(row0 + r0) * K + kq;
  const float* aptr1 = Af + (size_t)(row0 + r1) * K + kq;

  float acc[8][8] = {};
  int ty = tid >> 4, tx = tid & 15;

  for (int k0 = 0; k0 < K; k0 += BK) {
    float4 a0 = *(const float4*)(aptr0 + k0);
    float4 a1 = *(const float4*)(aptr1 + k0);
    As[kq + 0][r0] = a0.x; As[kq + 1][r0] = a0.y; As[kq + 2][r0] = a0.z; As[kq + 3][r0] = a0.w;
    As[kq + 0][r1] = a1.x; As[kq + 1][r1] = a1.y; As[kq + 2][r1] = a1.z; As[kq + 3][r1] = a1.w;
    float4 b0 = *(const float4*)(wptr0 + k0);
    float4 b1 = *(const float4*)(wptr1 + k0);
    Bs[wkq + 0][wrl] = b0.x; Bs[wkq + 1][wrl] = b0.y; Bs[wkq + 2][wrl] = b0.z; Bs[wkq + 3][wrl] = b0.w;
    Bs[wkq + 0][wrl + 64] = b1.x; Bs[wkq + 1][wrl + 64] = b1.y; Bs[wkq + 2][wrl + 64] = b1.z; Bs[wkq + 3][wrl + 64] = b1.w;
    __syncthreads();
#pragma unroll
    for (int kk = 0; kk < BK; ++kk) {
      float4 a0v = *(const float4*)&As[kk][ty * 8];
      float4 a1v = *(const float4*)&As[kk][ty * 8 + 4];
      float4 b0v = *(const float4*)&Bs[kk][tx * 8];
      float4 b1v = *(const float4*)&Bs[kk][tx * 8 + 4];
      float av[8] = {a0v.x, a0v.y, a0v.z, a0v.w, a1v.x, a1v.y, a1v.z, a1v.w};
      float bv[8] = {b0v.x, b0v.y, b0v.z, b0v.w, b1v.x, b1v.y, b1v.z, b1v.w};
#pragma unroll
      for (int i = 0; i < 8; ++i)
#pragma unroll
        for (int j = 0; j < 8; ++j) acc[i][j] = fmaf(av[i], bv[j], acc[i][j]);
    }
    __syncthreads();
  }

#pragma unroll
  for (int i = 0; i < 8; ++i) {
    int grow = row0 + ty * 8 + i;
    size_t cidx = (size_t)grow * N + col0 + tx * 8;
    float4 o0 = make_float4(acc[i][0], acc[i][1], acc[i][2], acc[i][3]);
    float4 o1 = make_float4(acc[i][4], acc[i][5], acc[i][6], acc[i][7]);
    if (MODE == 1) {
      float4 d0 = *(const float4*)(addend + cidx);
      float4 d1 = *(const float4*)(addend + cidx + 4);
      o0.x += d0.x; o0.y += d0.y; o0.z += d0.z; o0.w += d0.w;
      o1.x += d1.x; o1.y += d1.y; o1.z += d1.z; o1.w += d1.w;
    }
    *(float4*)(Cf + cidx) = o0;
    *(float4*)(Cf + cidx + 4) = o1;
  }
}

// ---------------------------------------------------------------- bf16 MFMA grouped GEMM (MoE)
// C[cnt_e, N] = A[*, K] @ W_e[N, K]^T   (m97 structure: 128x128 tile, BK=64, 4 waves)
// MODE 0 (FFN1): A rows gathered via tok2e>>1 from hnb; epilogue silu -> bf16 hmid[base+r]
// MODE 1 (FFN2): A = hmid rows base+r;   epilogue bf16 y[tok2e[base+r]]
template <int MODE>
__global__ __launch_bounds__(256)
void moe_mfma(const unsigned short* __restrict__ A, const unsigned short* __restrict__ Wb,
              unsigned short* __restrict__ Cout, const int* __restrict__ tok2e,
              const int* __restrict__ ebase, const int* __restrict__ icnt) {
  constexpr int N = (MODE == 0) ? DFF2 : DMODEL;
  constexpr int K = (MODE == 0) ? DMODEL : DFF2;
  __shared__ __align__(16) unsigned short As[128 * 64];
  __shared__ __align__(16) unsigned short Bs[128 * 64];
  int e = blockIdx.z;
  int base = ebase[e];
  int cnt = icnt[e];
  int row0 = blockIdx.y * 128;
  if (row0 >= cnt) return;
  int col0 = blockIdx.x * 128;
  int tid = threadIdx.x;
  int w = tid >> 6, l = tid & 63;
  int lr = l >> 3;        // row within 8-row group
  int lc = (l & 7) * 8;   // element col offset (16B chunks)

  const unsigned short* aSrc[4];
  const unsigned short* bSrc[4];
#pragma unroll
  for (int i = 0; i < 4; ++i) {
    int r = row0 + i * 32 + w * 8 + lr;
    r = r < cnt ? r : cnt - 1;
    if (MODE == 0) {
      int tok = tok2e[base + r] >> 1;
      aSrc[i] = A + (size_t)tok * K + lc;
    } else {
      aSrc[i] = A + (size_t)(base + r) * K + lc;
    }
    int nrow = col0 + i * 32 + w * 8 + lr;
    bSrc[i] = Wb + (size_t)e * N * K + (size_t)nrow * K + lc;
  }

  f32x4 acc[4][4] = {};
  int wr = w >> 1, wc = w & 1;
  int ln16 = l & 15, lq = l >> 4;

  for (int k0 = 0; k0 < K; k0 += 64) {
#pragma unroll
    for (int i = 0; i < 4; ++i) {
      gload_lds16(aSrc[i] + k0, &As[(i * 4 + w) * 512]);
      gload_lds16(bSrc[i] + k0, &Bs[(i * 4 + w) * 512]);
    }
    __syncthreads();
#pragma unroll
    for (int kk = 0; kk < 2; ++kk) {
      bf16x8 af[4], bfr[4];
#pragma unroll
      for (int m = 0; m < 4; ++m)
        af[m] = *(const bf16x8*)&As[(wr * 64 + m * 16 + ln16) * 64 + kk * 32 + lq * 8];
#pragma unroll
      for (int n = 0; n < 4; ++n)
        bfr[n] = *(const bf16x8*)&Bs[(wc * 64 + n * 16 + ln16) * 64 + kk * 32 + lq * 8];
#pragma unroll
      for (int m = 0; m < 4; ++m)
#pragma unroll
        for (int n = 0; n < 4; ++n)
          acc[m][n] = __builtin_amdgcn_mfma_f32_16x16x32_bf16(af[m], bfr[n], acc[m][n], 0, 0, 0);
    }
    __syncthreads();
  }

#pragma unroll
  for (int m = 0; m < 4; ++m) {
#pragma unroll
    for (int j = 0; j < 4; ++j) {
      int r = row0 + wr * 64 + m * 16 + lq * 4 + j;
      if (r < cnt) {
        if (MODE == 0) {
          unsigned short* orow = Cout + (size_t)(base + r) * N + col0 + wc * 64 + ln16;
#pragma unroll
          for (int n = 0; n < 4; ++n) {
            float v = acc[m][n][j];
            float s = v / (1.f + __expf(-v));
            orow[n * 16] = f2bf(s);
          }
        } else {
          int t2 = tok2e[base + r];
          unsigned short* orow = Cout + (size_t)t2 * N + col0 + wc * 64 + ln16;
#pragma unroll
          for (int n = 0; n < 4; ++n) orow[n * 16] = f2bf(acc[m][n][j]);
        }
      }
    }
  }
}

// ---------------------------------------------------------------- f32 -> bf16 weight conversion
__global__ __launch_bounds__(256)
void cvt_bf16_kernel(const float* __restrict__ in, unsigned short* __restrict__ o, int n8) {
  int stride = gridDim.x * 256;
  for (int i = blockIdx.x * 256 + threadIdx.x; i < n8; i += stride) {
    float4 a = ((const float4*)in)[2 * i];
    float4 b = ((const float4*)in)[2 * i + 1];
    ushort8v u;
    u[0] = f2bf(a.x); u[1] = f2bf(a.y); u[2] = f2bf(a.z); u[3] = f2bf(a.w);
    u[4] = f2bf(b.x); u[5] = f2bf(b.y); u[6] = f2bf(b.z); u[7] = f2bf(b.w);
    *(ushort8v*)(o + (size_t)i * 8) = u;
  }
}

// ---------------------------------------------------------------- rope (cos-only, per reference) + ksum = k_c + roped k_r ; q *= 0.125
__global__ __launch_bounds__(256)
void rope_kernel(float* __restrict__ q, float* __restrict__ k,
                 const float* __restrict__ kc, const float* __restrict__ tsq,
                 const float* __restrict__ tskv) {
  int t = blockIdx.x;
  int tid = threadIdx.x;
  __shared__ float cq[32], ck[32];
  if (tid < 32) {
    float fr = __expf(-(float)(2 * tid) * (1.0f / HD) * 9.210340371976184f);  // ln(10000)
    cq[tid] = cosf(tsq[t] * fr);
    ck[tid] = cosf(tskv[t] * fr);
  }
  __syncthreads();
  size_t rb = (size_t)t * DMODEL;
  for (int p = tid; p < 512; p += 256) {
    int hh = p >> 5, d = p & 31;
    int c1 = hh * 64 + d, c2 = c1 + 32;
    float cqd = cq[d], ckd = ck[d];
    float q1 = q[rb + c1], q2 = q[rb + c2];
    q[rb + c1] = (q1 * cqd - q2 * ckd) * 0.125f;
    q[rb + c2] = (q2 * cqd + q1 * ckd) * 0.125f;
    float k1 = k[rb + c1], k2 = k[rb + c2];
    k[rb + c1] = (k1 * cqd - k2 * ckd) + kc[rb + c1];
    k[rb + c2] = (k2 * cqd + k1 * ckd) + kc[rb + c2];
  }
}

// ---------------------------------------------------------------- fused attention (f32, exact path)
__global__ __launch_bounds__(256)
void attn_kernel(const float* __restrict__ q, const float* __restrict__ k,
                 const float* __restrict__ v, float* __restrict__ out) {
  __shared__ float sc[4][LSEQ];
  __shared__ float qs[4][HD];
  __shared__ float4 klds4[64 * 16];
  __shared__ float red[16][HD];
  __shared__ float sinv[4];
  int b = blockIdx.z, h = blockIdx.y;
  int lq0 = blockIdx.x * 4;
  int tid = threadIdx.x;
  int lane = tid & 63, wid = tid >> 6;
  size_t basebh = (size_t)b * LSEQ * DMODEL + h * HD;

  qs[wid][lane] = q[basebh + (size_t)(lq0 + wid) * DMODEL + lane];
  __syncthreads();

  float4 qreg[16];
#pragma unroll
  for (int c = 0; c < 16; ++c) qreg[c] = *(const float4*)&qs[wid][c * 4];

  for (int kt = 0; kt < 16; ++kt) {
    int lr = tid >> 2;
    int c0 = (tid & 3) * 4;
    const float4* src = (const float4*)(k + basebh + (size_t)(kt * 64 + lr) * DMODEL) + c0;
#pragma unroll
    for (int i = 0; i < 4; ++i) klds4[lr * 16 + ((c0 + i) ^ (lr & 15))] = src[i];
    __syncthreads();
    float s = 0.f;
#pragma unroll
    for (int c = 0; c < 16; ++c) {
      float4 kv4 = klds4[lane * 16 + (c ^ (lane & 15))];
      float4 qv4 = qreg[c];
      s += qv4.x * kv4.x + qv4.y * kv4.y + qv4.z * kv4.z + qv4.w * kv4.w;
    }
    sc[wid][kt * 64 + lane] = s;
    __syncthreads();
  }

  {
    float m = -1e30f;
    for (int kk = lane; kk < LSEQ; kk += 64) m = fmaxf(m, sc[wid][kk]);
#pragma unroll
    for (int off = 32; off > 0; off >>= 1) m = fmaxf(m, __shfl_xor(m, off));
    float sum = 0.f;
    for (int kk = lane; kk < LSEQ; kk += 64) {
      float p = __expf(sc[wid][kk] - m);
      sc[wid][kk] = p;
      sum += p;
    }
#pragma unroll
    for (int off = 32; off > 0; off >>= 1) sum += __shfl_xor(sum, off);
    if (lane == 0) sinv[wid] = 1.0f / sum;
  }
  __syncthreads();

  {
    float a0 = 0.f, a1 = 0.f, a2 = 0.f, a3 = 0.f;
    const float* vb = v + basebh + lane;
    int kbeg = wid * 256;
    for (int kk = kbeg; kk < kbeg + 256; kk += 4) {
      float4 p0 = *(const float4*)&sc[0][kk];
      float4 p1 = *(const float4*)&sc[1][kk];
      float4 p2 = *(const float4*)&sc[2][kk];
      float4 p3 = *(const float4*)&sc[3][kk];
      float v0 = vb[(size_t)(kk + 0) * DMODEL];
      float v1 = vb[(size_t)(kk + 1) * DMODEL];
      float v2 = vb[(size_t)(kk + 2) * DMODEL];
      float v3 = vb[(size_t)(kk + 3) * DMODEL];
      a0 += p0.x * v0 + p0.y * v1 + p0.z * v2 + p0.w * v3;
      a1 += p1.x * v0 + p1.y * v1 + p1.z * v2 + p1.w * v3;
      a2 += p2.x * v0 + p2.y * v1 + p2.z * v2 + p2.w * v3;
      a3 += p3.x * v0 + p3.y * v1 + p3.z * v2 + p3.w * v3;
    }
    red[wid * 4 + 0][lane] = a0;
    red[wid * 4 + 1][lane] = a1;
    red[wid * 4 + 2][lane] = a2;
    red[wid * 4 + 3][lane] = a3;
  }
  __syncthreads();
  {
    float o = (red[0 * 4 + wid][lane] + red[1 * 4 + wid][lane] +
               red[2 * 4 + wid][lane] + red[3 * 4 + wid][lane]) * sinv[wid];
    out[basebh + (size_t)(lq0 + wid) * DMODEL + lane] = o;
  }
}

// ---------------------------------------------------------------- gating (exact f32), top-2, counts
__global__ __launch_bounds__(256)
void gate_kernel(const float* __restrict__ hn, const float* __restrict__ gw,
                 const float* __restrict__ bias, int* __restrict__ ti,
                 float* __restrict__ tw, int* __restrict__ icnt,
                 float* __restrict__ counts_out) {
  int t = blockIdx.x * 4 + (threadIdx.x >> 6);
  int lane = threadIdx.x & 63;
  const float* hrow = hn + (size_t)t * DMODEL;
  float acc[NEXP];
#pragma unroll
  for (int e = 0; e < NEXP; ++e) acc[e] = 0.f;
  for (int d = lane; d < DMODEL; d += 64) {
    float hv = hrow[d];
#pragma unroll
    for (int e = 0; e < NEXP; ++e) acc[e] += hv * gw[e * DMODEL + d];
  }
#pragma unroll
  for (int e = 0; e < NEXP; ++e)
#pragma unroll
    for (int off = 32; off > 0; off >>= 1) acc[e] += __shfl_xor(acc[e], off);
  if (lane == 0) {
    float l[NEXP], ex[NEXP];
    float mx = -1e30f;
#pragma unroll
    for (int e = 0; e < NEXP; ++e) {
      l[e] = acc[e] + bias[e];
      mx = fmaxf(mx, l[e]);
    }
#pragma unroll
    for (int e = 0; e < NEXP; ++e) ex[e] = expf(l[e] - mx);
    int i0 = 0;
    float p0 = ex[0];
#pragma unroll
    for (int e = 1; e < NEXP; ++e)
      if (ex[e] > p0) { p0 = ex[e]; i0 = e; }
    int i1 = -1;
    float p1 = -1.f;
#pragma unroll
    for (int e = 0; e < NEXP; ++e)
      if (e != i0 && ex[e] > p1) { p1 = ex[e]; i1 = e; }
    float wsum = p0 + p1;
    ti[2 * t] = i0;
    ti[2 * t + 1] = i1;
    tw[2 * t] = p0 / wsum;
    tw[2 * t + 1] = p1 / wsum;
    atomicAdd(&icnt[i0], 1);
    atomicAdd(&icnt[i1], 1);
    atomicAdd(&counts_out[i0], 1.0f);
    atomicAdd(&counts_out[i1], 1.0f);
  }
}

__global__ void init_kernel(float* __restrict__ counts_out, int* __restrict__ icnt,
                            int* __restrict__ cursor) {
  int i = threadIdx.x;
  if (i < NEXP) {
    counts_out[i] = 0.f;
    icnt[i] = 0;
    cursor[i] = 0;
  }
}

__global__ void scan_kernel(const int* __restrict__ icnt, int* __restrict__ ebase) {
  if (threadIdx.x == 0) {
    int s = 0;
    for (int e = 0; e < NEXP; ++e) {
      ebase[e] = s;
      s += icnt[e];
    }
  }
}

__global__ __launch_bounds__(256)
void scatter_kernel(const int* __restrict__ ti, const int* __restrict__ ebase,
                    int* __restrict__ cursor, int* __restrict__ tok2e) {
  int t = blockIdx.x * 256 + threadIdx.x;
#pragma unroll
  for (int s = 0; s < 2; ++s) {
    int e = ti[2 * t + s];
    int pos = atomicAdd(&cursor[e], 1);
    tok2e[ebase[e] + pos] = 2 * t + s;
  }
}

// out = x1 + tw0*y[2t] + tw1*y[2t+1]   (y in bf16)
__global__ __launch_bounds__(256)
void combine_kernel(const float* __restrict__ x1, const unsigned short* __restrict__ y,
                    const float* __restrict__ tw, float* __restrict__ out) {
  int idx = blockIdx.x * 256 + threadIdx.x;
  int t = idx >> 8, c = idx & 255;
  float w0 = tw[2 * t], w1 = tw[2 * t + 1];
  float4 a = ((const float4*)x1)[idx];
  const unsigned short* y0 = y + (size_t)(2 * t) * DMODEL + c * 4;
  const unsigned short* y1 = y0 + DMODEL;
  ushort4 u0 = *(const ushort4*)y0;
  ushort4 u1 = *(const ushort4*)y1;
  float4 o;
  o.x = a.x + w0 * bf2f(u0.x) + w1 * bf2f(u1.x);
  o.y = a.y + w0 * bf2f(u0.y) + w1 * bf2f(u1.y);
  o.z = a.z + w0 * bf2f(u0.z) + w1 * bf2f(u1.z);
  o.w = a.w + w0 * bf2f(u0.w) + w1 * bf2f(u1.w);
  ((float4*)out)[idx] = o;
}

// ----------------------------------------------------------------
extern "C" void kernel_launch(void* const* d_in, const int* in_sizes, int n_in,
                              void* d_out, int out_size, void* d_ws, size_t ws_size,
                              hipStream_t stream) {
  (void)in_sizes; (void)n_in; (void)ws_size;
  const float* x = (const float*)d_in[0];
  const float* tsq = (const float*)d_in[1];
  const float* tskv = (const float*)d_in[2];
  const float* attn_nw = (const float*)d_in[3];
  const float* ffn_nw = (const float*)d_in[4];
  const float* w_kv_c = (const float*)d_in[5];
  const float* w_kc_up = (const float*)d_in[6];
  const float* w_vc_up = (const float*)d_in[7];
  const float* w_qr = (const float*)d_in[8];
  const float* w_kr = (const float*)d_in[9];
  const float* w_o = (const float*)d_in[10];
  const float* gate_w = (const float*)d_in[11];
  const float* expert_bias = (const float*)d_in[12];
  const float* w1 = (const float*)d_in[13];
  const float* w2 = (const float*)d_in[14];

  float* out = (float*)d_out;
  float* counts_out = out + (out_size - NEXP);

  char* ws = (char*)d_ws;
  size_t off = 0;
  auto alloc = [&](size_t bytes) {
    char* p = ws + off;
    off += (bytes + 255) & ~(size_t)255;
    return p;
  };
  float* h   = (float*)alloc((size_t)NTOK * DMODEL * 4);   // h, later x1
  float* qb  = (float*)alloc((size_t)NTOK * DMODEL * 4);   // q_r, later hn; then w1b/w2b overlay
  float* kb  = (float*)alloc((size_t)NTOK * DMODEL * 4);   // k_r -> ksum
  float* vb  = (float*)alloc((size_t)NTOK * DMODEL * 4);   // v_c
  float* kcb = (float*)alloc((size_t)NTOK * DMODEL * 4);   // k_c, later attn_out
  float* ckv = (float*)alloc((size_t)NTOK * DC * 4);
  unsigned short* yb  = (unsigned short*)alloc((size_t)NTOK * 2 * DMODEL * 2);  // bf16 y
  unsigned short* hnb = (unsigned short*)alloc((size_t)NTOK * DMODEL * 2);      // bf16 hn
  unsigned short* hmid = (unsigned short*)alloc((size_t)NTOK * 2 * DFF2 * 2);   // bf16
  float* tw  = (float*)alloc((size_t)NTOK * 2 * 4);
  int* ti    = (int*)alloc((size_t)NTOK * 2 * 4);
  int* tok2e = (int*)alloc((size_t)NTOK * 2 * 4);
  int* icnt  = (int*)alloc(NEXP * 4);
  int* ebase = (int*)alloc(NEXP * 4);
  int* cursor = (int*)alloc(NEXP * 4);
  // 64MB bf16 weight overlay on qb..kcb (dead after gate / after FFN1)
  unsigned short* wxb = (unsigned short*)qb;

  init_kernel<<<1, 64, 0, stream>>>(counts_out, icnt, cursor);
  rmsnorm_kernel<<<NTOK, 256, 0, stream>>>(x, attn_nw, h, nullptr);
  // projections (f32 exact path — protects top-2 routing)
  gemm_bt<0><<<dim3(DC / 128, NTOK / 128), 256, 0, stream>>>(h, w_kv_c, ckv, nullptr, NTOK, DC, DMODEL);
  gemm_bt<0><<<dim3(DMODEL / 128, NTOK / 128), 256, 0, stream>>>(h, w_qr, qb, nullptr, NTOK, DMODEL, DMODEL);
  gemm_bt<0><<<dim3(DMODEL / 128, NTOK / 128), 256, 0, stream>>>(h, w_kr, kb, nullptr, NTOK, DMODEL, DMODEL);
  gemm_bt<0><<<dim3(DMODEL / 128, NTOK / 128), 256, 0, stream>>>(ckv, w_kc_up, kcb, nullptr, NTOK, DMODEL, DC);
  gemm_bt<0><<<dim3(DMODEL / 128, NTOK / 128), 256, 0, stream>>>(ckv, w_vc_up, vb, nullptr, NTOK, DMODEL, DC);
  rope_kernel<<<NTOK, 256, 0, stream>>>(qb, kb, kcb, tsq, tskv);
  attn_kernel<<<dim3(LSEQ / 4, NHEADS, NBATCH), 256, 0, stream>>>(qb, kb, vb, kcb);
  gemm_bt<1><<<dim3(DMODEL / 128, NTOK / 128), 256, 0, stream>>>(kcb, w_o, h, x, NTOK, DMODEL, DMODEL);
  rmsnorm_kernel<<<NTOK, 256, 0, stream>>>(h, ffn_nw, qb, hnb);  // hn (f32 for gate) + bf16 for FFN1
  gate_kernel<<<NTOK / 4, 256, 0, stream>>>(qb, gate_w, expert_bias, ti, tw, icnt, counts_out);
  scan_kernel<<<1, 64, 0, stream>>>(icnt, ebase);
  scatter_kernel<<<NTOK / 256, 256, 0, stream>>>(ti, ebase, cursor, tok2e);
  // w1 -> bf16 (qb region now dead)
  cvt_bf16_kernel<<<2048, 256, 0, stream>>>(w1, wxb, NEXP * DFF2 * DMODEL / 8);
  moe_mfma<0><<<dim3(DFF2 / 128, NTOK / 128, NEXP), 256, 0, stream>>>(hnb, wxb, hmid, tok2e, ebase, icnt);
  // w2 -> bf16 (same overlay region, w1b dead after FFN1)
  cvt_bf16_kernel<<<2048, 256, 0, stream>>>(w2, wxb, NEXP * DMODEL * DFF2 / 8);
  moe_mfma<1><<<dim3(DMODEL / 128, NTOK / 128, NEXP), 256, 0, stream>>>(hmid, wxb, yb, tok2e, ebase, icnt);
  combine_kernel<<<NTOK, 256, 0, stream>>>(h, yb, tw, out);
}

// Round 4
// 1069.148 us; speedup vs baseline: 3.6000x; 1.8008x over previous
//
#include <hip/hip_runtime.h>
#include <hip/hip_bf16.h>

typedef __hip_bfloat16 bf16;
typedef __attribute__((ext_vector_type(8))) unsigned short ushort8v;
typedef __bf16 bf16x8 __attribute__((ext_vector_type(8)));
typedef float f32x4 __attribute__((ext_vector_type(4)));

#define NTOK 4096
#define DMODEL 1024
#define NHEADS 16
#define HD 64
#define DC 128
#define DFF2 4096
#define NEXP 8
#define LSEQ 1024
#define NBATCH 4
#define RMS_EPS 1.1920928955078125e-07f

union U8 { ushort8v u; bf16x8 b; };

__device__ __forceinline__ float bf2f(unsigned short u) {
  return __uint_as_float(((unsigned int)u) << 16);
}
__device__ __forceinline__ unsigned short f2bf(float f) {
  unsigned int u = __float_as_uint(f);
  unsigned int r = (u + 0x7FFF + ((u >> 16) & 1)) >> 16;
  return (unsigned short)r;
}
__device__ __forceinline__ void split1(float v, unsigned short& hi, unsigned short& lo) {
  hi = f2bf(v);
  float r = v - bf2f(hi);
  lo = f2bf(r);
}
__device__ __forceinline__ void split4(float4 v, ushort4& hi, ushort4& lo) {
  split1(v.x, hi.x, lo.x);
  split1(v.y, hi.y, lo.y);
  split1(v.z, hi.z, lo.z);
  split1(v.w, hi.w, lo.w);
}
__device__ __forceinline__ void gload_lds16(const unsigned short* g, unsigned short* l) {
  __builtin_amdgcn_global_load_lds(
      (__attribute__((address_space(1))) void*)(const_cast<unsigned short*>(g)),
      (__attribute__((address_space(3))) void*)(l), 16, 0, 0);
}

// ---------------------------------------------------------------- rmsnorm (optional extra bf16 output)
__global__ __launch_bounds__(256)
void rmsnorm_kernel(const float* __restrict__ x, const float* __restrict__ w,
                    float* __restrict__ o, unsigned short* __restrict__ ob) {
  int t = blockIdx.x;
  int tid = threadIdx.x;
  const float4* xr = (const float4*)(x + (size_t)t * DMODEL);
  float4 v = xr[tid];
  float ss = v.x * v.x + v.y * v.y + v.z * v.z + v.w * v.w;
#pragma unroll
  for (int off = 32; off > 0; off >>= 1) ss += __shfl_xor(ss, off);
  __shared__ float red[4];
  int wid = tid >> 6, lane = tid & 63;
  if (lane == 0) red[wid] = ss;
  __syncthreads();
  float tot = red[0] + red[1] + red[2] + red[3];
  float scale = rsqrtf(tot * (1.0f / DMODEL) + RMS_EPS);
  float4 wv = ((const float4*)w)[tid];
  float4 ov;
  ov.x = v.x * scale * wv.x;
  ov.y = v.y * scale * wv.y;
  ov.z = v.z * scale * wv.z;
  ov.w = v.w * scale * wv.w;
  ((float4*)(o + (size_t)t * DMODEL))[tid] = ov;
  if (ob) {
    unsigned short* orow = ob + (size_t)t * DMODEL + tid * 4;
    orow[0] = f2bf(ov.x); orow[1] = f2bf(ov.y);
    orow[2] = f2bf(ov.z); orow[3] = f2bf(ov.w);
  }
}

// ---------------------------------------------------------------- split-expand
// VAR 0 (activations): out[rows][3K] = [hi|hi|lo]
// VAR 1 (weights):     out[rows][3K] = [hi|lo|hi]
// dot over 3K = Ah.Wh + Ah.Wl + Al.Wh  (correct 3-term Markidis split)
template <int VAR>
__global__ __launch_bounds__(256)
void expand_kernel(const float* __restrict__ A, unsigned short* __restrict__ out,
                   int K, int total4) {
  int idx = blockIdx.x * 256 + threadIdx.x;
  if (idx >= total4) return;
  int K4 = K >> 2;
  int m = idx / K4;
  int k4 = idx - m * K4;
  float4 v = *(const float4*)(A + (size_t)m * K + k4 * 4);
  ushort4 hi, lo;
  split4(v, hi, lo);
  size_t base = (size_t)m * (3 * K) + k4 * 4;
  *(ushort4*)(out + base) = hi;
  if (VAR == 0) {
    *(ushort4*)(out + base + K) = hi;
    *(ushort4*)(out + base + 2 * K) = lo;
  } else {
    *(ushort4*)(out + base + K) = lo;
    *(ushort4*)(out + base + 2 * K) = hi;
  }
}

// ---------------------------------------------------------------- dense split-bf16 MFMA GEMM
// C[4096, N] f32 (+addend) = Aexp[4096, Kexp] . Wexp[N, Kexp]^T   (m97 structure)
__global__ __launch_bounds__(256)
void gemm_split(const unsigned short* __restrict__ Aexp, const unsigned short* __restrict__ Wexp,
                float* __restrict__ Cf, const float* __restrict__ addend, int N, int Kexp) {
  __shared__ __align__(16) unsigned short As[128 * 64];
  __shared__ __align__(16) unsigned short Bs[128 * 64];
  int row0 = blockIdx.y * 128;
  int col0 = blockIdx.x * 128;
  int tid = threadIdx.x;
  int w = tid >> 6, l = tid & 63;
  int lr = l >> 3;
  int lc = (l & 7) * 8;

  const unsigned short* aSrc[4];
  const unsigned short* bSrc[4];
#pragma unroll
  for (int i = 0; i < 4; ++i) {
    aSrc[i] = Aexp + (size_t)(row0 + i * 32 + w * 8 + lr) * Kexp + lc;
    bSrc[i] = Wexp + (size_t)(col0 + i * 32 + w * 8 + lr) * Kexp + lc;
  }

  f32x4 acc[4][4] = {};
  int wr = w >> 1, wc = w & 1;
  int ln = l & 15, lq = l >> 4;

  for (int k0 = 0; k0 < Kexp; k0 += 64) {
#pragma unroll
    for (int i = 0; i < 4; ++i) {
      gload_lds16(aSrc[i] + k0, &As[(i * 4 + w) * 512]);
      gload_lds16(bSrc[i] + k0, &Bs[(i * 4 + w) * 512]);
    }
    __syncthreads();
#pragma unroll
    for (int kk = 0; kk < 2; ++kk) {
      bf16x8 af[4], bfr[4];
#pragma unroll
      for (int m = 0; m < 4; ++m)
        af[m] = *(const bf16x8*)&As[(wr * 64 + m * 16 + ln) * 64 + kk * 32 + lq * 8];
#pragma unroll
      for (int n = 0; n < 4; ++n)
        bfr[n] = *(const bf16x8*)&Bs[(wc * 64 + n * 16 + ln) * 64 + kk * 32 + lq * 8];
#pragma unroll
      for (int m = 0; m < 4; ++m)
#pragma unroll
        for (int n = 0; n < 4; ++n)
          acc[m][n] = __builtin_amdgcn_mfma_f32_16x16x32_bf16(af[m], bfr[n], acc[m][n], 0, 0, 0);
    }
    __syncthreads();
  }

#pragma unroll
  for (int m = 0; m < 4; ++m) {
#pragma unroll
    for (int j = 0; j < 4; ++j) {
      int row = row0 + wr * 64 + m * 16 + lq * 4 + j;
      float* crow = Cf + (size_t)row * N + col0 + wc * 64 + ln;
      const float* arow = addend ? addend + (size_t)row * N + col0 + wc * 64 + ln : nullptr;
#pragma unroll
      for (int n = 0; n < 4; ++n) {
        float vv = acc[m][n][j];
        if (addend) vv += arow[n * 16];
        crow[n * 16] = vv;
      }
    }
  }
}

// ---------------------------------------------------------------- bf16 MFMA grouped GEMM (MoE)
template <int MODE>
__global__ __launch_bounds__(256)
void moe_mfma(const unsigned short* __restrict__ A, const unsigned short* __restrict__ Wb,
              unsigned short* __restrict__ Cout, const int* __restrict__ tok2e,
              const int* __restrict__ ebase, const int* __restrict__ icnt) {
  constexpr int N = (MODE == 0) ? DFF2 : DMODEL;
  constexpr int K = (MODE == 0) ? DMODEL : DFF2;
  __shared__ __align__(16) unsigned short As[128 * 64];
  __shared__ __align__(16) unsigned short Bs[128 * 64];
  int e = blockIdx.z;
  int base = ebase[e];
  int cnt = icnt[e];
  int row0 = blockIdx.y * 128;
  if (row0 >= cnt) return;
  int col0 = blockIdx.x * 128;
  int tid = threadIdx.x;
  int w = tid >> 6, l = tid & 63;
  int lr = l >> 3;
  int lc = (l & 7) * 8;

  const unsigned short* aSrc[4];
  const unsigned short* bSrc[4];
#pragma unroll
  for (int i = 0; i < 4; ++i) {
    int r = row0 + i * 32 + w * 8 + lr;
    r = r < cnt ? r : cnt - 1;
    if (MODE == 0) {
      int tok = tok2e[base + r] >> 1;
      aSrc[i] = A + (size_t)tok * K + lc;
    } else {
      aSrc[i] = A + (size_t)(base + r) * K + lc;
    }
    int nrow = col0 + i * 32 + w * 8 + lr;
    bSrc[i] = Wb + (size_t)e * N * K + (size_t)nrow * K + lc;
  }

  f32x4 acc[4][4] = {};
  int wr = w >> 1, wc = w & 1;
  int ln16 = l & 15, lq = l >> 4;

  for (int k0 = 0; k0 < K; k0 += 64) {
#pragma unroll
    for (int i = 0; i < 4; ++i) {
      gload_lds16(aSrc[i] + k0, &As[(i * 4 + w) * 512]);
      gload_lds16(bSrc[i] + k0, &Bs[(i * 4 + w) * 512]);
    }
    __syncthreads();
#pragma unroll
    for (int kk = 0; kk < 2; ++kk) {
      bf16x8 af[4], bfr[4];
#pragma unroll
      for (int m = 0; m < 4; ++m)
        af[m] = *(const bf16x8*)&As[(wr * 64 + m * 16 + ln16) * 64 + kk * 32 + lq * 8];
#pragma unroll
      for (int n = 0; n < 4; ++n)
        bfr[n] = *(const bf16x8*)&Bs[(wc * 64 + n * 16 + ln16) * 64 + kk * 32 + lq * 8];
#pragma unroll
      for (int m = 0; m < 4; ++m)
#pragma unroll
        for (int n = 0; n < 4; ++n)
          acc[m][n] = __builtin_amdgcn_mfma_f32_16x16x32_bf16(af[m], bfr[n], acc[m][n], 0, 0, 0);
    }
    __syncthreads();
  }

#pragma unroll
  for (int m = 0; m < 4; ++m) {
#pragma unroll
    for (int j = 0; j < 4; ++j) {
      int r = row0 + wr * 64 + m * 16 + lq * 4 + j;
      if (r < cnt) {
        if (MODE == 0) {
          unsigned short* orow = Cout + (size_t)(base + r) * N + col0 + wc * 64 + ln16;
#pragma unroll
          for (int n = 0; n < 4; ++n) {
            float v = acc[m][n][j];
            float s = v / (1.f + __expf(-v));
            orow[n * 16] = f2bf(s);
          }
        } else {
          int t2 = tok2e[base + r];
          unsigned short* orow = Cout + (size_t)t2 * N + col0 + wc * 64 + ln16;
#pragma unroll
          for (int n = 0; n < 4; ++n) orow[n * 16] = f2bf(acc[m][n][j]);
        }
      }
    }
  }
}

// ---------------------------------------------------------------- f32 -> bf16 weight conversion (MoE weights)
__global__ __launch_bounds__(256)
void cvt_bf16_kernel(const float* __restrict__ in, unsigned short* __restrict__ o, int n8) {
  int stride = gridDim.x * 256;
  for (int i = blockIdx.x * 256 + threadIdx.x; i < n8; i += stride) {
    float4 a = ((const float4*)in)[2 * i];
    float4 b = ((const float4*)in)[2 * i + 1];
    ushort8v u;
    u[0] = f2bf(a.x); u[1] = f2bf(a.y); u[2] = f2bf(a.z); u[3] = f2bf(a.w);
    u[4] = f2bf(b.x); u[5] = f2bf(b.y); u[6] = f2bf(b.z); u[7] = f2bf(b.w);
    *(ushort8v*)(o + (size_t)i * 8) = u;
  }
}

// ---------------------------------------------------------------- rope (cos-only, per reference) + ksum = k_c + roped k_r ; q *= 0.125
__global__ __launch_bounds__(256)
void rope_kernel(float* __restrict__ q, float* __restrict__ k,
                 const float* __restrict__ kc, const float* __restrict__ tsq,
                 const float* __restrict__ tskv) {
  int t = blockIdx.x;
  int tid = threadIdx.x;
  __shared__ float cq[32], ck[32];
  if (tid < 32) {
    float fr = __expf(-(float)(2 * tid) * (1.0f / HD) * 9.210340371976184f);  // ln(10000)
    cq[tid] = cosf(tsq[t] * fr);
    ck[tid] = cosf(tskv[t] * fr);
  }
  __syncthreads();
  size_t rb = (size_t)t * DMODEL;
  for (int p = tid; p < 512; p += 256) {
    int hh = p >> 5, d = p & 31;
    int c1 = hh * 64 + d, c2 = c1 + 32;
    float cqd = cq[d], ckd = ck[d];
    float q1 = q[rb + c1], q2 = q[rb + c2];
    q[rb + c1] = (q1 * cqd - q2 * ckd) * 0.125f;
    q[rb + c2] = (q2 * cqd + q1 * ckd) * 0.125f;
    float k1 = k[rb + c1], k2 = k[rb + c2];
    k[rb + c1] = (k1 * cqd - k2 * ckd) + kc[rb + c1];
    k[rb + c2] = (k2 * cqd + k1 * ckd) + kc[rb + c2];
  }
}

// ---------------------------------------------------------------- q/k split to per-(b,h) bf16 hi/lo  [bh][l][64]
__global__ __launch_bounds__(256)
void qk_split_kernel(const float* __restrict__ q, const float* __restrict__ k,
                     unsigned short* __restrict__ Qh, unsigned short* __restrict__ Ql,
                     unsigned short* __restrict__ Kh, unsigned short* __restrict__ Kl) {
  int t = blockIdx.x;
  int b = t >> 10, lrow = t & 1023;
  int tid = threadIdx.x;
  int c = tid * 4;
  int hh = c >> 6, d = c & 63;
  size_t src = (size_t)t * DMODEL + c;
  size_t dst = ((size_t)(b * NHEADS + hh) * LSEQ + lrow) * HD + d;
  float4 qv = *(const float4*)(q + src);
  float4 kv = *(const float4*)(k + src);
  ushort4 hi, lo;
  split4(qv, hi, lo);
  *(ushort4*)(Qh + dst) = hi;
  *(ushort4*)(Ql + dst) = lo;
  split4(kv, hi, lo);
  *(ushort4*)(Kh + dst) = hi;
  *(ushort4*)(Kl + dst) = lo;
}

// ---------------------------------------------------------------- v split + transpose  [bh][64][1024]
__global__ __launch_bounds__(256)
void v_split_kernel(const float* __restrict__ v, unsigned short* __restrict__ Vth,
                    unsigned short* __restrict__ Vtl) {
  __shared__ float tile[128][65];
  int bh = blockIdx.x;
  int lt = blockIdx.y;
  int b = bh >> 4, hh = bh & 15;
  int tid = threadIdx.x;
#pragma unroll
  for (int pass = 0; pass < 8; ++pass) {
    int r = pass * 16 + (tid >> 4);
    int dq = (tid & 15) * 4;
    float4 vv = *(const float4*)(v + (size_t)(b * 1024 + lt * 128 + r) * DMODEL + hh * 64 + dq);
    tile[r][dq + 0] = vv.x; tile[r][dq + 1] = vv.y;
    tile[r][dq + 2] = vv.z; tile[r][dq + 3] = vv.w;
  }
  __syncthreads();
  int d = tid >> 2, seg = (tid & 3) * 32;
  size_t obase = ((size_t)bh * HD + d) * LSEQ + lt * 128 + seg;
  for (int i = 0; i < 32; i += 4) {
    float4 vv = make_float4(tile[seg + i][d], tile[seg + i + 1][d],
                            tile[seg + i + 2][d], tile[seg + i + 3][d]);
    ushort4 hi, lo;
    split4(vv, hi, lo);
    *(ushort4*)(Vth + obase + i) = hi;
    *(ushort4*)(Vtl + obase + i) = lo;
  }
}

// ---------------------------------------------------------------- split-bf16 MFMA flash attention
__global__ __launch_bounds__(256, 2)
void attn_mfma(const unsigned short* __restrict__ Qh, const unsigned short* __restrict__ Ql,
               const unsigned short* __restrict__ Kh, const unsigned short* __restrict__ Kl,
               const unsigned short* __restrict__ Vth, const unsigned short* __restrict__ Vtl,
               float* __restrict__ out) {
  __shared__ unsigned int plds[128 * 128];  // packed P (hi<<16|lo), 32B-XOR swizzled
  int bh = blockIdx.y;
  int qt = blockIdx.x;
  int tid = threadIdx.x;
  int w = tid >> 6, l = tid & 63;
  int ln = l & 15, lq = l >> 4;
  size_t kvbase = (size_t)bh * LSEQ * HD;
  int qrow0 = qt * 128 + w * 32;

  bf16x8 qh[2][2], qlo[2][2];
#pragma unroll
  for (int mi = 0; mi < 2; ++mi)
#pragma unroll
    for (int ks = 0; ks < 2; ++ks) {
      size_t o = kvbase + (size_t)(qrow0 + mi * 16 + ln) * HD + ks * 32 + lq * 8;
      qh[mi][ks] = *(const bf16x8*)(Qh + o);
      qlo[mi][ks] = *(const bf16x8*)(Ql + o);
    }

  float l_run[2][4] = {};
  f32x4 oacc[2][4] = {};

  for (int kt = 0; kt < 8; ++kt) {
    int k0 = kt * 128;
    f32x4 sacc[2][8] = {};
#pragma unroll
    for (int ni = 0; ni < 8; ++ni) {
      size_t ko = kvbase + (size_t)(k0 + ni * 16 + ln) * HD + lq * 8;
      bf16x8 kh0 = *(const bf16x8*)(Kh + ko);
      bf16x8 kh1 = *(const bf16x8*)(Kh + ko + 32);
      bf16x8 kl0 = *(const bf16x8*)(Kl + ko);
      bf16x8 kl1 = *(const bf16x8*)(Kl + ko + 32);
#pragma unroll
      for (int mi = 0; mi < 2; ++mi) {
        f32x4 a = sacc[mi][ni];
        a = __builtin_amdgcn_mfma_f32_16x16x32_bf16(qh[mi][0], kh0, a, 0, 0, 0);
        a = __builtin_amdgcn_mfma_f32_16x16x32_bf16(qh[mi][1], kh1, a, 0, 0, 0);
        a = __builtin_amdgcn_mfma_f32_16x16x32_bf16(qh[mi][0], kl0, a, 0, 0, 0);
        a = __builtin_amdgcn_mfma_f32_16x16x32_bf16(qh[mi][1], kl1, a, 0, 0, 0);
        a = __builtin_amdgcn_mfma_f32_16x16x32_bf16(qlo[mi][0], kh0, a, 0, 0, 0);
        a = __builtin_amdgcn_mfma_f32_16x16x32_bf16(qlo[mi][1], kh1, a, 0, 0, 0);
        sacc[mi][ni] = a;
      }
    }
#pragma unroll
    for (int mi = 0; mi < 2; ++mi)
#pragma unroll
      for (int j = 0; j < 4; ++j) {
        float rs = 0.f;
#pragma unroll
        for (int ni = 0; ni < 8; ++ni) {
          float p = __expf(sacc[mi][ni][j]);
          sacc[mi][ni][j] = p;
          rs += p;
        }
        rs += __shfl_xor(rs, 1);
        rs += __shfl_xor(rs, 2);
        rs += __shfl_xor(rs, 4);
        rs += __shfl_xor(rs, 8);
        l_run[mi][j] += rs;
      }
#pragma unroll
    for (int mi = 0; mi < 2; ++mi)
#pragma unroll
      for (int ni = 0; ni < 8; ++ni)
#pragma unroll
        for (int j = 0; j < 4; ++j) {
          int row = w * 32 + mi * 16 + lq * 4 + j;
          int col = ni * 16 + ln;
          float p = sacc[mi][ni][j];
          unsigned int ab = __float_as_uint(p);
          unsigned int hib = ab & 0xffff0000u;
          float r = p - __uint_as_float(hib);
          unsigned int u = hib | (__float_as_uint(r) >> 16);
          plds[row * 128 + (col ^ ((row & 3) << 3))] = u;
        }
    __syncthreads();
#pragma unroll
    for (int ksp = 0; ksp < 4; ++ksp) {
      bf16x8 ph[2], pl[2];
#pragma unroll
      for (int mi = 0; mi < 2; ++mi) {
        int row = w * 32 + mi * 16 + ln;
        int c0 = ksp * 32 + lq * 8;
        const unsigned int* pp = &plds[row * 128 + (c0 ^ ((row & 3) << 3))];
        uint4 u0 = *(const uint4*)pp;
        uint4 u1 = *(const uint4*)(pp + 4);
        unsigned int uu[8] = {u0.x, u0.y, u0.z, u0.w, u1.x, u1.y, u1.z, u1.w};
        U8 uh, ul;
#pragma unroll
        for (int jj = 0; jj < 8; ++jj) {
          uh.u[jj] = (unsigned short)(uu[jj] >> 16);
          ul.u[jj] = (unsigned short)(uu[jj] & 0xffffu);
        }
        ph[mi] = uh.b;
        pl[mi] = ul.b;
      }
#pragma unroll
      for (int ni = 0; ni < 4; ++ni) {
        size_t vo = kvbase + (size_t)(ni * 16 + ln) * LSEQ + k0 + ksp * 32 + lq * 8;
        bf16x8 vh = *(const bf16x8*)(Vth + vo);
        bf16x8 vl = *(const bf16x8*)(Vtl + vo);
#pragma unroll
        for (int mi = 0; mi < 2; ++mi) {
          f32x4 a = oacc[mi][ni];
          a = __builtin_amdgcn_mfma_f32_16x16x32_bf16(ph[mi], vh, a, 0, 0, 0);
          a = __builtin_amdgcn_mfma_f32_16x16x32_bf16(ph[mi], vl, a, 0, 0, 0);
          a = __builtin_amdgcn_mfma_f32_16x16x32_bf16(pl[mi], vh, a, 0, 0, 0);
          oacc[mi][ni] = a;
        }
      }
    }
    __syncthreads();
  }

  int b = bh >> 4, hh = bh & 15;
#pragma unroll
  for (int mi = 0; mi < 2; ++mi) {
    float inv[4];
#pragma unroll
    for (int j = 0; j < 4; ++j) inv[j] = 1.0f / l_run[mi][j];
#pragma unroll
    for (int ni = 0; ni < 4; ++ni)
#pragma unroll
      for (int j = 0; j < 4; ++j) {
        int tok = b * 1024 + qt * 128 + w * 32 + mi * 16 + lq * 4 + j;
        int col = hh * 64 + ni * 16 + ln;
        out[(size_t)tok * DMODEL + col] = oacc[mi][ni][j] * inv[j];
      }
  }
}

// ---------------------------------------------------------------- gating (exact f32), top-2, counts
__global__ __launch_bounds__(256)
void gate_kernel(const float* __restrict__ hn, const float* __restrict__ gw,
                 const float* __restrict__ bias, int* __restrict__ ti,
                 float* __restrict__ tw, int* __restrict__ icnt,
                 float* __restrict__ counts_out) {
  int t = blockIdx.x * 4 + (threadIdx.x >> 6);
  int lane = threadIdx.x & 63;
  const float* hrow = hn + (size_t)t * DMODEL;
  float acc[NEXP];
#pragma unroll
  for (int e = 0; e < NEXP; ++e) acc[e] = 0.f;
  for (int d = lane; d < DMODEL; d += 64) {
    float hv = hrow[d];
#pragma unroll
    for (int e = 0; e < NEXP; ++e) acc[e] += hv * gw[e * DMODEL + d];
  }
#pragma unroll
  for (int e = 0; e < NEXP; ++e)
#pragma unroll
    for (int off = 32; off > 0; off >>= 1) acc[e] += __shfl_xor(acc[e], off);
  if (lane == 0) {
    float lg[NEXP], ex[NEXP];
    float mx = -1e30f;
#pragma unroll
    for (int e = 0; e < NEXP; ++e) {
      lg[e] = acc[e] + bias[e];
      mx = fmaxf(mx, lg[e]);
    }
#pragma unroll
    for (int e = 0; e < NEXP; ++e) ex[e] = expf(lg[e] - mx);
    int i0 = 0;
    float p0 = ex[0];
#pragma unroll
    for (int e = 1; e < NEXP; ++e)
      if (ex[e] > p0) { p0 = ex[e]; i0 = e; }
    int i1 = -1;
    float p1 = -1.f;
#pragma unroll
    for (int e = 0; e < NEXP; ++e)
      if (e != i0 && ex[e] > p1) { p1 = ex[e]; i1 = e; }
    float wsum = p0 + p1;
    ti[2 * t] = i0;
    ti[2 * t + 1] = i1;
    tw[2 * t] = p0 / wsum;
    tw[2 * t + 1] = p1 / wsum;
    atomicAdd(&icnt[i0], 1);
    atomicAdd(&icnt[i1], 1);
    atomicAdd(&counts_out[i0], 1.0f);
    atomicAdd(&counts_out[i1], 1.0f);
  }
}

__global__ void init_kernel(float* __restrict__ counts_out, int* __restrict__ icnt,
                            int* __restrict__ cursor) {
  int i = threadIdx.x;
  if (i < NEXP) {
    counts_out[i] = 0.f;
    icnt[i] = 0;
    cursor[i] = 0;
  }
}

__global__ void scan_kernel(const int* __restrict__ icnt, int* __restrict__ ebase) {
  if (threadIdx.x == 0) {
    int s = 0;
    for (int e = 0; e < NEXP; ++e) {
      ebase[e] = s;
      s += icnt[e];
    }
  }
}

__global__ __launch_bounds__(256)
void scatter_kernel(const int* __restrict__ ti, const int* __restrict__ ebase,
                    int* __restrict__ cursor, int* __restrict__ tok2e) {
  int t = blockIdx.x * 256 + threadIdx.x;
#pragma unroll
  for (int s = 0; s < 2; ++s) {
    int e = ti[2 * t + s];
    int pos = atomicAdd(&cursor[e], 1);
    tok2e[ebase[e] + pos] = 2 * t + s;
  }
}

// out = x1 + tw0*y[2t] + tw1*y[2t+1]   (y in bf16)
__global__ __launch_bounds__(256)
void combine_kernel(const float* __restrict__ x1, const unsigned short* __restrict__ y,
                    const float* __restrict__ tw, float* __restrict__ out) {
  int idx = blockIdx.x * 256 + threadIdx.x;
  int t = idx >> 8, c = idx & 255;
  float w0 = tw[2 * t], w1 = tw[2 * t + 1];
  float4 a = ((const float4*)x1)[idx];
  const unsigned short* y0 = y + (size_t)(2 * t) * DMODEL + c * 4;
  const unsigned short* y1 = y0 + DMODEL;
  ushort4 u0 = *(const ushort4*)y0;
  ushort4 u1 = *(const ushort4*)y1;
  float4 o;
  o.x = a.x + w0 * bf2f(u0.x) + w1 * bf2f(u1.x);
  o.y = a.y + w0 * bf2f(u0.y) + w1 * bf2f(u1.y);
  o.z = a.z + w0 * bf2f(u0.z) + w1 * bf2f(u1.z);
  o.w = a.w + w0 * bf2f(u0.w) + w1 * bf2f(u1.w);
  ((float4*)out)[idx] = o;
}

// ----------------------------------------------------------------
extern "C" void kernel_launch(void* const* d_in, const int* in_sizes, int n_in,
                              void* d_out, int out_size, void* d_ws, size_t ws_size,
                              hipStream_t stream) {
  (void)in_sizes; (void)n_in; (void)ws_size;
  const float* x = (const float*)d_in[0];
  const float* tsq = (const float*)d_in[1];
  const float* tskv = (const float*)d_in[2];
  const float* attn_nw = (const float*)d_in[3];
  const float* ffn_nw = (const float*)d_in[4];
  const float* w_kv_c = (const float*)d_in[5];
  const float* w_kc_up = (const float*)d_in[6];
  const float* w_vc_up = (const float*)d_in[7];
  const float* w_qr = (const float*)d_in[8];
  const float* w_kr = (const float*)d_in[9];
  const float* w_o = (const float*)d_in[10];
  const float* gate_w = (const float*)d_in[11];
  const float* expert_bias = (const float*)d_in[12];
  const float* w1 = (const float*)d_in[13];
  const float* w2 = (const float*)d_in[14];

  float* out = (float*)d_out;
  float* counts_out = out + (out_size - NEXP);

  char* ws = (char*)d_ws;
  size_t off = 0;
  auto alloc = [&](size_t bytes) {
    char* p = ws + off;
    off += (bytes + 255) & ~(size_t)255;
    return p;
  };
  float* h   = (float*)alloc((size_t)NTOK * DMODEL * 4);   // h, later x1
  float* qb  = (float*)alloc((size_t)NTOK * DMODEL * 4);   // q_r, later hn; then MoE wxb overlay
  float* kb  = (float*)alloc((size_t)NTOK * DMODEL * 4);   // k_r -> ksum
  float* vb  = (float*)alloc((size_t)NTOK * DMODEL * 4);   // v_c
  float* kcb = (float*)alloc((size_t)NTOK * DMODEL * 4);   // k_c, later attn_out
  float* ckv = (float*)alloc((size_t)NTOK * DC * 4);
  unsigned short* yb  = (unsigned short*)alloc((size_t)NTOK * 2 * DMODEL * 2);  // bf16 y
  unsigned short* hnb = (unsigned short*)alloc((size_t)NTOK * DMODEL * 2);      // bf16 hn
  unsigned short* hmid = (unsigned short*)alloc((size_t)NTOK * 2 * DFF2 * 2);   // bf16
  float* tw  = (float*)alloc((size_t)NTOK * 2 * 4);
  int* ti    = (int*)alloc((size_t)NTOK * 2 * 4);
  int* tok2e = (int*)alloc((size_t)NTOK * 2 * 4);
  int* icnt  = (int*)alloc(NEXP * 4);
  int* ebase = (int*)alloc(NEXP * 4);
  int* cursor = (int*)alloc(NEXP * 4);
  unsigned short* hexp   = (unsigned short*)alloc((size_t)NTOK * 3 * DMODEL * 2);  // 24MB
  unsigned short* ckvexp = (unsigned short*)alloc((size_t)NTOK * 3 * DC * 2);      // 3MB
  unsigned short* wbuf   = (unsigned short*)alloc((size_t)DMODEL * 3 * DMODEL * 2);// 6MB

  // attention split buffers overlay hnb+hmid (dead until after attention)
  unsigned short* Qh  = hnb;
  unsigned short* Ql  = hmid;
  unsigned short* Kh  = hmid + (size_t)4 * 1024 * 1024;
  unsigned short* Kl  = hmid + (size_t)8 * 1024 * 1024;
  unsigned short* Vth = hmid + (size_t)12 * 1024 * 1024;
  unsigned short* Vtl = hmid + (size_t)16 * 1024 * 1024;
  // MoE weight overlay on qb..kcb (64MB, dead after gate)
  unsigned short* wxb = (unsigned short*)qb;

  init_kernel<<<1, 64, 0, stream>>>(counts_out, icnt, cursor);
  rmsnorm_kernel<<<NTOK, 256, 0, stream>>>(x, attn_nw, h, nullptr);
  expand_kernel<0><<<NTOK, 256, 0, stream>>>(h, hexp, DMODEL, NTOK * DMODEL / 4);
  // q_r
  expand_kernel<1><<<DMODEL, 256, 0, stream>>>(w_qr, wbuf, DMODEL, DMODEL * DMODEL / 4);
  gemm_split<<<dim3(8, 32), 256, 0, stream>>>(hexp, wbuf, qb, nullptr, DMODEL, 3 * DMODEL);
  // k_r
  expand_kernel<1><<<DMODEL, 256, 0, stream>>>(w_kr, wbuf, DMODEL, DMODEL * DMODEL / 4);
  gemm_split<<<dim3(8, 32), 256, 0, stream>>>(hexp, wbuf, kb, nullptr, DMODEL, 3 * DMODEL);
  // c_kv
  expand_kernel<1><<<DC, 256, 0, stream>>>(w_kv_c, wbuf, DMODEL, DC * DMODEL / 4);
  gemm_split<<<dim3(1, 32), 256, 0, stream>>>(hexp, wbuf, ckv, nullptr, DC, 3 * DMODEL);
  expand_kernel<0><<<512, 256, 0, stream>>>(ckv, ckvexp, DC, NTOK * DC / 4);
  // k_c
  expand_kernel<1><<<128, 256, 0, stream>>>(w_kc_up, wbuf, DC, DMODEL * DC / 4);
  gemm_split<<<dim3(8, 32), 256, 0, stream>>>(ckvexp, wbuf, kcb, nullptr, DMODEL, 3 * DC);
  // v_c
  expand_kernel<1><<<128, 256, 0, stream>>>(w_vc_up, wbuf, DC, DMODEL * DC / 4);
  gemm_split<<<dim3(8, 32), 256, 0, stream>>>(ckvexp, wbuf, vb, nullptr, DMODEL, 3 * DC);
  // rope + ksum
  rope_kernel<<<NTOK, 256, 0, stream>>>(qb, kb, kcb, tsq, tskv);
  // attention (split-bf16 MFMA)
  qk_split_kernel<<<NTOK, 256, 0, stream>>>(qb, kb, Qh, Ql, Kh, Kl);
  v_split_kernel<<<dim3(64, 8), 256, 0, stream>>>(vb, Vth, Vtl);
  attn_mfma<<<dim3(8, 64), 256, 0, stream>>>(Qh, Ql, Kh, Kl, Vth, Vtl, kcb);
  // w_o + residual
  expand_kernel<0><<<NTOK, 256, 0, stream>>>(kcb, hexp, DMODEL, NTOK * DMODEL / 4);
  expand_kernel<1><<<DMODEL, 256, 0, stream>>>(w_o, wbuf, DMODEL, DMODEL * DMODEL / 4);
  gemm_split<<<dim3(8, 32), 256, 0, stream>>>(hexp, wbuf, h, x, DMODEL, 3 * DMODEL);
  // FFN norm + gate + route
  rmsnorm_kernel<<<NTOK, 256, 0, stream>>>(h, ffn_nw, qb, hnb);
  gate_kernel<<<NTOK / 4, 256, 0, stream>>>(qb, gate_w, expert_bias, ti, tw, icnt, counts_out);
  scan_kernel<<<1, 64, 0, stream>>>(icnt, ebase);
  scatter_kernel<<<NTOK / 256, 256, 0, stream>>>(ti, ebase, cursor, tok2e);
  // MoE
  cvt_bf16_kernel<<<2048, 256, 0, stream>>>(w1, wxb, NEXP * DFF2 * DMODEL / 8);
  moe_mfma<0><<<dim3(DFF2 / 128, NTOK / 128, NEXP), 256, 0, stream>>>(hnb, wxb, hmid, tok2e, ebase, icnt);
  cvt_bf16_kernel<<<2048, 256, 0, stream>>>(w2, wxb, NEXP * DMODEL * DFF2 / 8);
  moe_mfma<1><<<dim3(DMODEL / 128, NTOK / 128, NEXP), 256, 0, stream>>>(hmid, wxb, yb, tok2e, ebase, icnt);
  combine_kernel<<<NTOK, 256, 0, stream>>>(h, yb, tw, out);
}

// Round 5
// 814.949 us; speedup vs baseline: 4.7230x; 1.3119x over previous
//
#include <hip/hip_runtime.h>
#include <hip/hip_bf16.h>

typedef __hip_bfloat16 bf16;
typedef __attribute__((ext_vector_type(8))) unsigned short ushort8v;
typedef __bf16 bf16x8 __attribute__((ext_vector_type(8)));
typedef float f32x4 __attribute__((ext_vector_type(4)));

#define NTOK 4096
#define DMODEL 1024
#define NHEADS 16
#define HD 64
#define DC 128
#define DFF2 4096
#define NEXP 8
#define LSEQ 1024
#define NBATCH 4
#define RMS_EPS 1.1920928955078125e-07f

union U8 { ushort8v u; bf16x8 b; };

__device__ __forceinline__ float bf2f(unsigned short u) {
  return __uint_as_float(((unsigned int)u) << 16);
}
__device__ __forceinline__ unsigned short f2bf(float f) {
  unsigned int u = __float_as_uint(f);
  unsigned int r = (u + 0x7FFF + ((u >> 16) & 1)) >> 16;
  return (unsigned short)r;
}
__device__ __forceinline__ void gload_lds16(const unsigned short* g, unsigned short* l) {
  __builtin_amdgcn_global_load_lds(
      (__attribute__((address_space(1))) void*)(const_cast<unsigned short*>(g)),
      (__attribute__((address_space(3))) void*)(l), 16, 0, 0);
}

// ---------------------------------------------------------------- rmsnorm (optional extra bf16 output)
__global__ __launch_bounds__(256)
void rmsnorm_kernel(const float* __restrict__ x, const float* __restrict__ w,
                    float* __restrict__ o, unsigned short* __restrict__ ob) {
  int t = blockIdx.x;
  int tid = threadIdx.x;
  const float4* xr = (const float4*)(x + (size_t)t * DMODEL);
  float4 v = xr[tid];
  float ss = v.x * v.x + v.y * v.y + v.z * v.z + v.w * v.w;
#pragma unroll
  for (int off = 32; off > 0; off >>= 1) ss += __shfl_xor(ss, off);
  __shared__ float red[4];
  int wid = tid >> 6, lane = tid & 63;
  if (lane == 0) red[wid] = ss;
  __syncthreads();
  float tot = red[0] + red[1] + red[2] + red[3];
  float scale = rsqrtf(tot * (1.0f / DMODEL) + RMS_EPS);
  float4 wv = ((const float4*)w)[tid];
  float4 ov;
  ov.x = v.x * scale * wv.x;
  ov.y = v.y * scale * wv.y;
  ov.z = v.z * scale * wv.z;
  ov.w = v.w * scale * wv.w;
  if (o) ((float4*)(o + (size_t)t * DMODEL))[tid] = ov;
  if (ob) {
    unsigned short* orow = ob + (size_t)t * DMODEL + tid * 4;
    orow[0] = f2bf(ov.x); orow[1] = f2bf(ov.y);
    orow[2] = f2bf(ov.z); orow[3] = f2bf(ov.w);
  }
}

// ---------------------------------------------------------------- f32 -> bf16 conversion (weights / activations)
__global__ __launch_bounds__(256)
void cvt_bf16_kernel(const float* __restrict__ in, unsigned short* __restrict__ o, int n8) {
  int stride = gridDim.x * 256;
  for (int i = blockIdx.x * 256 + threadIdx.x; i < n8; i += stride) {
    float4 a = ((const float4*)in)[2 * i];
    float4 b = ((const float4*)in)[2 * i + 1];
    ushort8v u;
    u[0] = f2bf(a.x); u[1] = f2bf(a.y); u[2] = f2bf(a.z); u[3] = f2bf(a.w);
    u[4] = f2bf(b.x); u[5] = f2bf(b.y); u[6] = f2bf(b.z); u[7] = f2bf(b.w);
    *(ushort8v*)(o + (size_t)i * 8) = u;
  }
}

// ---------------------------------------------------------------- dense bf16 MFMA GEMM (m97 structure)
// C[M=4096, N] f32 (+addend) = Ab[4096, K] . Wb[N, K]^T
__global__ __launch_bounds__(256)
void gemm_bf16(const unsigned short* __restrict__ Ab, const unsigned short* __restrict__ Wb,
               float* __restrict__ Cf, const float* __restrict__ addend, int N, int K) {
  __shared__ __align__(16) unsigned short As[128 * 64];
  __shared__ __align__(16) unsigned short Bs[128 * 64];
  int row0 = blockIdx.y * 128;
  int col0 = blockIdx.x * 128;
  int tid = threadIdx.x;
  int w = tid >> 6, l = tid & 63;
  int lr = l >> 3;
  int lc = (l & 7) * 8;

  const unsigned short* aSrc[4];
  const unsigned short* bSrc[4];
#pragma unroll
  for (int i = 0; i < 4; ++i) {
    aSrc[i] = Ab + (size_t)(row0 + i * 32 + w * 8 + lr) * K + lc;
    bSrc[i] = Wb + (size_t)(col0 + i * 32 + w * 8 + lr) * K + lc;
  }

  f32x4 acc[4][4] = {};
  int wr = w >> 1, wc = w & 1;
  int ln = l & 15, lq = l >> 4;

  for (int k0 = 0; k0 < K; k0 += 64) {
#pragma unroll
    for (int i = 0; i < 4; ++i) {
      gload_lds16(aSrc[i] + k0, &As[(i * 4 + w) * 512]);
      gload_lds16(bSrc[i] + k0, &Bs[(i * 4 + w) * 512]);
    }
    __syncthreads();
#pragma unroll
    for (int kk = 0; kk < 2; ++kk) {
      bf16x8 af[4], bfr[4];
#pragma unroll
      for (int m = 0; m < 4; ++m)
        af[m] = *(const bf16x8*)&As[(wr * 64 + m * 16 + ln) * 64 + kk * 32 + lq * 8];
#pragma unroll
      for (int n = 0; n < 4; ++n)
        bfr[n] = *(const bf16x8*)&Bs[(wc * 64 + n * 16 + ln) * 64 + kk * 32 + lq * 8];
#pragma unroll
      for (int m = 0; m < 4; ++m)
#pragma unroll
        for (int n = 0; n < 4; ++n)
          acc[m][n] = __builtin_amdgcn_mfma_f32_16x16x32_bf16(af[m], bfr[n], acc[m][n], 0, 0, 0);
    }
    __syncthreads();
  }

#pragma unroll
  for (int m = 0; m < 4; ++m) {
#pragma unroll
    for (int j = 0; j < 4; ++j) {
      int row = row0 + wr * 64 + m * 16 + lq * 4 + j;
      float* crow = Cf + (size_t)row * N + col0 + wc * 64 + ln;
      const float* arow = addend ? addend + (size_t)row * N + col0 + wc * 64 + ln : nullptr;
#pragma unroll
      for (int n = 0; n < 4; ++n) {
        float vv = acc[m][n][j];
        if (addend) vv += arow[n * 16];
        crow[n * 16] = vv;
      }
    }
  }
}

// ---------------------------------------------------------------- bf16 MFMA grouped GEMM (MoE)
template <int MODE>
__global__ __launch_bounds__(256)
void moe_mfma(const unsigned short* __restrict__ A, const unsigned short* __restrict__ Wb,
              unsigned short* __restrict__ Cout, const int* __restrict__ tok2e,
              const int* __restrict__ ebase, const int* __restrict__ icnt) {
  constexpr int N = (MODE == 0) ? DFF2 : DMODEL;
  constexpr int K = (MODE == 0) ? DMODEL : DFF2;
  __shared__ __align__(16) unsigned short As[128 * 64];
  __shared__ __align__(16) unsigned short Bs[128 * 64];
  int e = blockIdx.z;
  int base = ebase[e];
  int cnt = icnt[e];
  int row0 = blockIdx.y * 128;
  if (row0 >= cnt) return;
  int col0 = blockIdx.x * 128;
  int tid = threadIdx.x;
  int w = tid >> 6, l = tid & 63;
  int lr = l >> 3;
  int lc = (l & 7) * 8;

  const unsigned short* aSrc[4];
  const unsigned short* bSrc[4];
#pragma unroll
  for (int i = 0; i < 4; ++i) {
    int r = row0 + i * 32 + w * 8 + lr;
    r = r < cnt ? r : cnt - 1;
    if (MODE == 0) {
      int tok = tok2e[base + r] >> 1;
      aSrc[i] = A + (size_t)tok * K + lc;
    } else {
      aSrc[i] = A + (size_t)(base + r) * K + lc;
    }
    int nrow = col0 + i * 32 + w * 8 + lr;
    bSrc[i] = Wb + (size_t)e * N * K + (size_t)nrow * K + lc;
  }

  f32x4 acc[4][4] = {};
  int wr = w >> 1, wc = w & 1;
  int ln16 = l & 15, lq = l >> 4;

  for (int k0 = 0; k0 < K; k0 += 64) {
#pragma unroll
    for (int i = 0; i < 4; ++i) {
      gload_lds16(aSrc[i] + k0, &As[(i * 4 + w) * 512]);
      gload_lds16(bSrc[i] + k0, &Bs[(i * 4 + w) * 512]);
    }
    __syncthreads();
#pragma unroll
    for (int kk = 0; kk < 2; ++kk) {
      bf16x8 af[4], bfr[4];
#pragma unroll
      for (int m = 0; m < 4; ++m)
        af[m] = *(const bf16x8*)&As[(wr * 64 + m * 16 + ln16) * 64 + kk * 32 + lq * 8];
#pragma unroll
      for (int n = 0; n < 4; ++n)
        bfr[n] = *(const bf16x8*)&Bs[(wc * 64 + n * 16 + ln16) * 64 + kk * 32 + lq * 8];
#pragma unroll
      for (int m = 0; m < 4; ++m)
#pragma unroll
        for (int n = 0; n < 4; ++n)
          acc[m][n] = __builtin_amdgcn_mfma_f32_16x16x32_bf16(af[m], bfr[n], acc[m][n], 0, 0, 0);
    }
    __syncthreads();
  }

#pragma unroll
  for (int m = 0; m < 4; ++m) {
#pragma unroll
    for (int j = 0; j < 4; ++j) {
      int r = row0 + wr * 64 + m * 16 + lq * 4 + j;
      if (r < cnt) {
        if (MODE == 0) {
          unsigned short* orow = Cout + (size_t)(base + r) * N + col0 + wc * 64 + ln16;
#pragma unroll
          for (int n = 0; n < 4; ++n) {
            float v = acc[m][n][j];
            float s = v / (1.f + __expf(-v));
            orow[n * 16] = f2bf(s);
          }
        } else {
          int t2 = tok2e[base + r];
          unsigned short* orow = Cout + (size_t)t2 * N + col0 + wc * 64 + ln16;
#pragma unroll
          for (int n = 0; n < 4; ++n) orow[n * 16] = f2bf(acc[m][n][j]);
        }
      }
    }
  }
}

// ---------------------------------------------------------------- rope (cos-only, per reference) + ksum = k_c + roped k_r ; q *= 0.125
__global__ __launch_bounds__(256)
void rope_kernel(float* __restrict__ q, float* __restrict__ k,
                 const float* __restrict__ kc, const float* __restrict__ tsq,
                 const float* __restrict__ tskv) {
  int t = blockIdx.x;
  int tid = threadIdx.x;
  __shared__ float cq[32], ck[32];
  if (tid < 32) {
    float fr = __expf(-(float)(2 * tid) * (1.0f / HD) * 9.210340371976184f);  // ln(10000)
    cq[tid] = cosf(tsq[t] * fr);
    ck[tid] = cosf(tskv[t] * fr);
  }
  __syncthreads();
  size_t rb = (size_t)t * DMODEL;
  for (int p = tid; p < 512; p += 256) {
    int hh = p >> 5, d = p & 31;
    int c1 = hh * 64 + d, c2 = c1 + 32;
    float cqd = cq[d], ckd = ck[d];
    float q1 = q[rb + c1], q2 = q[rb + c2];
    q[rb + c1] = (q1 * cqd - q2 * ckd) * 0.125f;
    q[rb + c2] = (q2 * cqd + q1 * ckd) * 0.125f;
    float k1 = k[rb + c1], k2 = k[rb + c2];
    k[rb + c1] = (k1 * cqd - k2 * ckd) + kc[rb + c1];
    k[rb + c2] = (k2 * cqd + k1 * ckd) + kc[rb + c2];
  }
}

// ---------------------------------------------------------------- q/k cast to per-(b,h) bf16  [bh][l][64]
__global__ __launch_bounds__(256)
void qk_split_kernel(const float* __restrict__ q, const float* __restrict__ k,
                     unsigned short* __restrict__ Qb, unsigned short* __restrict__ Kb) {
  int t = blockIdx.x;
  int b = t >> 10, lrow = t & 1023;
  int tid = threadIdx.x;
  int c = tid * 4;
  int hh = c >> 6, d = c & 63;
  size_t src = (size_t)t * DMODEL + c;
  size_t dst = ((size_t)(b * NHEADS + hh) * LSEQ + lrow) * HD + d;
  float4 qv = *(const float4*)(q + src);
  float4 kv = *(const float4*)(k + src);
  ushort4 u;
  u.x = f2bf(qv.x); u.y = f2bf(qv.y); u.z = f2bf(qv.z); u.w = f2bf(qv.w);
  *(ushort4*)(Qb + dst) = u;
  u.x = f2bf(kv.x); u.y = f2bf(kv.y); u.z = f2bf(kv.z); u.w = f2bf(kv.w);
  *(ushort4*)(Kb + dst) = u;
}

// ---------------------------------------------------------------- v cast + transpose  [bh][64][1024]
__global__ __launch_bounds__(256)
void v_split_kernel(const float* __restrict__ v, unsigned short* __restrict__ Vt) {
  __shared__ float tile[128][65];
  int bh = blockIdx.x;
  int lt = blockIdx.y;
  int b = bh >> 4, hh = bh & 15;
  int tid = threadIdx.x;
#pragma unroll
  for (int pass = 0; pass < 8; ++pass) {
    int r = pass * 16 + (tid >> 4);
    int dq = (tid & 15) * 4;
    float4 vv = *(const float4*)(v + (size_t)(b * 1024 + lt * 128 + r) * DMODEL + hh * 64 + dq);
    tile[r][dq + 0] = vv.x; tile[r][dq + 1] = vv.y;
    tile[r][dq + 2] = vv.z; tile[r][dq + 3] = vv.w;
  }
  __syncthreads();
  int d = tid >> 2, seg = (tid & 3) * 32;
  size_t obase = ((size_t)bh * HD + d) * LSEQ + lt * 128 + seg;
  for (int i = 0; i < 32; i += 4) {
    ushort4 u;
    u.x = f2bf(tile[seg + i][d]);
    u.y = f2bf(tile[seg + i + 1][d]);
    u.z = f2bf(tile[seg + i + 2][d]);
    u.w = f2bf(tile[seg + i + 3][d]);
    *(ushort4*)(Vt + obase + i) = u;
  }
}

// ---------------------------------------------------------------- bf16 MFMA flash attention (single-term)
// grid (8 qtiles, 64 bh), 256 thr. Q-tile 128 rows, K-tiles of 128 over 1024 keys.
__global__ __launch_bounds__(256, 2)
void attn_mfma(const unsigned short* __restrict__ Qb, const unsigned short* __restrict__ Kb,
               const unsigned short* __restrict__ Vt, unsigned short* __restrict__ ao) {
  __shared__ unsigned int plds[128 * 128];  // P in hi 16 bits, 32B-XOR swizzled
  int bh = blockIdx.y;
  int qt = blockIdx.x;
  int tid = threadIdx.x;
  int w = tid >> 6, l = tid & 63;
  int ln = l & 15, lq = l >> 4;
  size_t kvbase = (size_t)bh * LSEQ * HD;
  int qrow0 = qt * 128 + w * 32;

  bf16x8 qh[2][2];
#pragma unroll
  for (int mi = 0; mi < 2; ++mi)
#pragma unroll
    for (int ks = 0; ks < 2; ++ks) {
      size_t o = kvbase + (size_t)(qrow0 + mi * 16 + ln) * HD + ks * 32 + lq * 8;
      qh[mi][ks] = *(const bf16x8*)(Qb + o);
    }

  float l_run[2][4] = {};
  f32x4 oacc[2][4] = {};

  for (int kt = 0; kt < 8; ++kt) {
    int k0 = kt * 128;
    f32x4 sacc[2][8] = {};
#pragma unroll
    for (int ni = 0; ni < 8; ++ni) {
      size_t ko = kvbase + (size_t)(k0 + ni * 16 + ln) * HD + lq * 8;
      bf16x8 kh0 = *(const bf16x8*)(Kb + ko);
      bf16x8 kh1 = *(const bf16x8*)(Kb + ko + 32);
#pragma unroll
      for (int mi = 0; mi < 2; ++mi) {
        f32x4 a = sacc[mi][ni];
        a = __builtin_amdgcn_mfma_f32_16x16x32_bf16(qh[mi][0], kh0, a, 0, 0, 0);
        a = __builtin_amdgcn_mfma_f32_16x16x32_bf16(qh[mi][1], kh1, a, 0, 0, 0);
        sacc[mi][ni] = a;
      }
    }
    // P = exp(S) (no max-subtract: |S| bounded small by construction), row-sum into l_run
#pragma unroll
    for (int mi = 0; mi < 2; ++mi)
#pragma unroll
      for (int j = 0; j < 4; ++j) {
        float rs = 0.f;
#pragma unroll
        for (int ni = 0; ni < 8; ++ni) {
          float p = __expf(sacc[mi][ni][j]);
          sacc[mi][ni][j] = p;
          rs += p;
        }
        rs += __shfl_xor(rs, 1);
        rs += __shfl_xor(rs, 2);
        rs += __shfl_xor(rs, 4);
        rs += __shfl_xor(rs, 8);
        l_run[mi][j] += rs;
      }
    // pack P (bf16 in hi bits) into swizzled LDS
#pragma unroll
    for (int mi = 0; mi < 2; ++mi)
#pragma unroll
      for (int ni = 0; ni < 8; ++ni)
#pragma unroll
        for (int j = 0; j < 4; ++j) {
          int row = w * 32 + mi * 16 + lq * 4 + j;
          int col = ni * 16 + ln;
          unsigned int u = ((unsigned int)f2bf(sacc[mi][ni][j])) << 16;
          plds[row * 128 + (col ^ ((row & 3) << 3))] = u;
        }
    __syncthreads();
    // O += P V
#pragma unroll
    for (int ksp = 0; ksp < 4; ++ksp) {
      bf16x8 ph[2];
#pragma unroll
      for (int mi = 0; mi < 2; ++mi) {
        int row = w * 32 + mi * 16 + ln;
        int c0 = ksp * 32 + lq * 8;
        const unsigned int* pp = &plds[row * 128 + (c0 ^ ((row & 3) << 3))];
        uint4 u0 = *(const uint4*)pp;
        uint4 u1 = *(const uint4*)(pp + 4);
        unsigned int uu[8] = {u0.x, u0.y, u0.z, u0.w, u1.x, u1.y, u1.z, u1.w};
        U8 uh;
#pragma unroll
        for (int jj = 0; jj < 8; ++jj) uh.u[jj] = (unsigned short)(uu[jj] >> 16);
        ph[mi] = uh.b;
      }
#pragma unroll
      for (int ni = 0; ni < 4; ++ni) {
        size_t vo = kvbase + (size_t)(ni * 16 + ln) * LSEQ + k0 + ksp * 32 + lq * 8;
        bf16x8 vh = *(const bf16x8*)(Vt + vo);
#pragma unroll
        for (int mi = 0; mi < 2; ++mi)
          oacc[mi][ni] = __builtin_amdgcn_mfma_f32_16x16x32_bf16(ph[mi], vh, oacc[mi][ni], 0, 0, 0);
      }
    }
    __syncthreads();
  }

  // epilogue: O / l_run -> ao (bf16) [token][DMODEL]
  int b = bh >> 4, hh = bh & 15;
#pragma unroll
  for (int mi = 0; mi < 2; ++mi) {
    float inv[4];
#pragma unroll
    for (int j = 0; j < 4; ++j) inv[j] = 1.0f / l_run[mi][j];
#pragma unroll
    for (int ni = 0; ni < 4; ++ni)
#pragma unroll
      for (int j = 0; j < 4; ++j) {
        int tok = b * 1024 + qt * 128 + w * 32 + mi * 16 + lq * 4 + j;
        int col = hh * 64 + ni * 16 + ln;
        ao[(size_t)tok * DMODEL + col] = f2bf(oacc[mi][ni][j] * inv[j]);
      }
  }
}

// ---------------------------------------------------------------- gating (exact f32), top-2, counts
__global__ __launch_bounds__(256)
void gate_kernel(const float* __restrict__ hn, const float* __restrict__ gw,
                 const float* __restrict__ bias, int* __restrict__ ti,
                 float* __restrict__ tw, int* __restrict__ icnt,
                 float* __restrict__ counts_out) {
  int t = blockIdx.x * 4 + (threadIdx.x >> 6);
  int lane = threadIdx.x & 63;
  const float* hrow = hn + (size_t)t * DMODEL;
  float acc[NEXP];
#pragma unroll
  for (int e = 0; e < NEXP; ++e) acc[e] = 0.f;
  for (int d = lane; d < DMODEL; d += 64) {
    float hv = hrow[d];
#pragma unroll
    for (int e = 0; e < NEXP; ++e) acc[e] += hv * gw[e * DMODEL + d];
  }
#pragma unroll
  for (int e = 0; e < NEXP; ++e)
#pragma unroll
    for (int off = 32; off > 0; off >>= 1) acc[e] += __shfl_xor(acc[e], off);
  if (lane == 0) {
    float lg[NEXP], ex[NEXP];
    float mx = -1e30f;
#pragma unroll
    for (int e = 0; e < NEXP; ++e) {
      lg[e] = acc[e] + bias[e];
      mx = fmaxf(mx, lg[e]);
    }
#pragma unroll
    for (int e = 0; e < NEXP; ++e) ex[e] = expf(lg[e] - mx);
    int i0 = 0;
    float p0 = ex[0];
#pragma unroll
    for (int e = 1; e < NEXP; ++e)
      if (ex[e] > p0) { p0 = ex[e]; i0 = e; }
    int i1 = -1;
    float p1 = -1.f;
#pragma unroll
    for (int e = 0; e < NEXP; ++e)
      if (e != i0 && ex[e] > p1) { p1 = ex[e]; i1 = e; }
    float wsum = p0 + p1;
    ti[2 * t] = i0;
    ti[2 * t + 1] = i1;
    tw[2 * t] = p0 / wsum;
    tw[2 * t + 1] = p1 / wsum;
    atomicAdd(&icnt[i0], 1);
    atomicAdd(&icnt[i1], 1);
    atomicAdd(&counts_out[i0], 1.0f);
    atomicAdd(&counts_out[i1], 1.0f);
  }
}

__global__ void init_kernel(float* __restrict__ counts_out, int* __restrict__ icnt,
                            int* __restrict__ cursor) {
  int i = threadIdx.x;
  if (i < NEXP) {
    counts_out[i] = 0.f;
    icnt[i] = 0;
    cursor[i] = 0;
  }
}

__global__ void scan_kernel(const int* __restrict__ icnt, int* __restrict__ ebase) {
  if (threadIdx.x == 0) {
    int s = 0;
    for (int e = 0; e < NEXP; ++e) {
      ebase[e] = s;
      s += icnt[e];
    }
  }
}

__global__ __launch_bounds__(256)
void scatter_kernel(const int* __restrict__ ti, const int* __restrict__ ebase,
                    int* __restrict__ cursor, int* __restrict__ tok2e) {
  int t = blockIdx.x * 256 + threadIdx.x;
#pragma unroll
  for (int s = 0; s < 2; ++s) {
    int e = ti[2 * t + s];
    int pos = atomicAdd(&cursor[e], 1);
    tok2e[ebase[e] + pos] = 2 * t + s;
  }
}

// out = x1 + tw0*y[2t] + tw1*y[2t+1]   (y in bf16)
__global__ __launch_bounds__(256)
void combine_kernel(const float* __restrict__ x1, const unsigned short* __restrict__ y,
                    const float* __restrict__ tw, float* __restrict__ out) {
  int idx = blockIdx.x * 256 + threadIdx.x;
  int t = idx >> 8, c = idx & 255;
  float w0 = tw[2 * t], w1 = tw[2 * t + 1];
  float4 a = ((const float4*)x1)[idx];
  const unsigned short* y0 = y + (size_t)(2 * t) * DMODEL + c * 4;
  const unsigned short* y1 = y0 + DMODEL;
  ushort4 u0 = *(const ushort4*)y0;
  ushort4 u1 = *(const ushort4*)y1;
  float4 o;
  o.x = a.x + w0 * bf2f(u0.x) + w1 * bf2f(u1.x);
  o.y = a.y + w0 * bf2f(u0.y) + w1 * bf2f(u1.y);
  o.z = a.z + w0 * bf2f(u0.z) + w1 * bf2f(u1.z);
  o.w = a.w + w0 * bf2f(u0.w) + w1 * bf2f(u1.w);
  ((float4*)out)[idx] = o;
}

// ----------------------------------------------------------------
extern "C" void kernel_launch(void* const* d_in, const int* in_sizes, int n_in,
                              void* d_out, int out_size, void* d_ws, size_t ws_size,
                              hipStream_t stream) {
  (void)in_sizes; (void)n_in; (void)ws_size;
  const float* x = (const float*)d_in[0];
  const float* tsq = (const float*)d_in[1];
  const float* tskv = (const float*)d_in[2];
  const float* attn_nw = (const float*)d_in[3];
  const float* ffn_nw = (const float*)d_in[4];
  const float* w_kv_c = (const float*)d_in[5];
  const float* w_kc_up = (const float*)d_in[6];
  const float* w_vc_up = (const float*)d_in[7];
  const float* w_qr = (const float*)d_in[8];
  const float* w_kr = (const float*)d_in[9];
  const float* w_o = (const float*)d_in[10];
  const float* gate_w = (const float*)d_in[11];
  const float* expert_bias = (const float*)d_in[12];
  const float* w1 = (const float*)d_in[13];
  const float* w2 = (const float*)d_in[14];

  float* out = (float*)d_out;
  float* counts_out = out + (out_size - NEXP);

  char* ws = (char*)d_ws;
  size_t off = 0;
  auto alloc = [&](size_t bytes) {
    char* p = ws + off;
    off += (bytes + 255) & ~(size_t)255;
    return p;
  };
  float* h   = (float*)alloc((size_t)NTOK * DMODEL * 4);   // h, later x1
  float* qb  = (float*)alloc((size_t)NTOK * DMODEL * 4);   // q_r, later hn; then MoE wxb overlay
  float* kb  = (float*)alloc((size_t)NTOK * DMODEL * 4);   // k_r -> ksum
  float* vb  = (float*)alloc((size_t)NTOK * DMODEL * 4);   // v_c
  float* kcb = (float*)alloc((size_t)NTOK * DMODEL * 4);   // k_c
  float* ckv = (float*)alloc((size_t)NTOK * DC * 4);
  unsigned short* yb  = (unsigned short*)alloc((size_t)NTOK * 2 * DMODEL * 2);  // bf16 y
  unsigned short* hb  = (unsigned short*)alloc((size_t)NTOK * DMODEL * 2);      // bf16 h / later hn (hnb)
  unsigned short* hmid = (unsigned short*)alloc((size_t)NTOK * 2 * DFF2 * 2);   // bf16, 64MB
  unsigned short* ckvb = (unsigned short*)alloc((size_t)NTOK * DC * 2);         // bf16 ckv
  unsigned short* wbuf = (unsigned short*)alloc((size_t)DMODEL * DMODEL * 2);   // bf16 weight staging (2MB)
  float* tw  = (float*)alloc((size_t)NTOK * 2 * 4);
  int* ti    = (int*)alloc((size_t)NTOK * 2 * 4);
  int* tok2e = (int*)alloc((size_t)NTOK * 2 * 4);
  int* icnt  = (int*)alloc(NEXP * 4);
  int* ebase = (int*)alloc(NEXP * 4);
  int* cursor = (int*)alloc(NEXP * 4);

  // attention buffers overlay hmid (dead until moe<0>): 4×8MB
  unsigned short* Qb = hmid;
  unsigned short* Kb = hmid + (size_t)4 * 1024 * 1024;
  unsigned short* Vt = hmid + (size_t)8 * 1024 * 1024;
  unsigned short* ao = hmid + (size_t)12 * 1024 * 1024;
  // MoE weight overlay on qb..kcb (64MB, dead after gate)
  unsigned short* wxb = (unsigned short*)qb;

  init_kernel<<<1, 64, 0, stream>>>(counts_out, icnt, cursor);
  rmsnorm_kernel<<<NTOK, 256, 0, stream>>>(x, attn_nw, nullptr, hb);
  // q_r = h @ w_qr^T
  cvt_bf16_kernel<<<512, 256, 0, stream>>>(w_qr, wbuf, DMODEL * DMODEL / 8);
  gemm_bf16<<<dim3(8, 32), 256, 0, stream>>>(hb, wbuf, qb, nullptr, DMODEL, DMODEL);
  // k_r = h @ w_kr^T
  cvt_bf16_kernel<<<512, 256, 0, stream>>>(w_kr, wbuf, DMODEL * DMODEL / 8);
  gemm_bf16<<<dim3(8, 32), 256, 0, stream>>>(hb, wbuf, kb, nullptr, DMODEL, DMODEL);
  // c_kv = h @ w_kv_c^T
  cvt_bf16_kernel<<<64, 256, 0, stream>>>(w_kv_c, wbuf, DC * DMODEL / 8);
  gemm_bf16<<<dim3(1, 32), 256, 0, stream>>>(hb, wbuf, ckv, nullptr, DC, DMODEL);
  cvt_bf16_kernel<<<256, 256, 0, stream>>>(ckv, ckvb, NTOK * DC / 8);
  // k_c = c_kv @ w_kc_up^T
  cvt_bf16_kernel<<<64, 256, 0, stream>>>(w_kc_up, wbuf, DMODEL * DC / 8);
  gemm_bf16<<<dim3(8, 32), 256, 0, stream>>>(ckvb, wbuf, kcb, nullptr, DMODEL, DC);
  // v_c = c_kv @ w_vc_up^T
  cvt_bf16_kernel<<<64, 256, 0, stream>>>(w_vc_up, wbuf, DMODEL * DC / 8);
  gemm_bf16<<<dim3(8, 32), 256, 0, stream>>>(ckvb, wbuf, vb, nullptr, DMODEL, DC);
  // rope + ksum (f32 exact)
  rope_kernel<<<NTOK, 256, 0, stream>>>(qb, kb, kcb, tsq, tskv);
  // attention (bf16 MFMA)
  qk_split_kernel<<<NTOK, 256, 0, stream>>>(qb, kb, Qb, Kb);
  v_split_kernel<<<dim3(64, 8), 256, 0, stream>>>(vb, Vt);
  attn_mfma<<<dim3(8, 64), 256, 0, stream>>>(Qb, Kb, Vt, ao);
  // x1 = attn_out @ w_o^T + x
  cvt_bf16_kernel<<<512, 256, 0, stream>>>(w_o, wbuf, DMODEL * DMODEL / 8);
  gemm_bf16<<<dim3(8, 32), 256, 0, stream>>>(ao, wbuf, h, x, DMODEL, DMODEL);
  // FFN norm + gate + route (f32 exact gate path)
  rmsnorm_kernel<<<NTOK, 256, 0, stream>>>(h, ffn_nw, qb, hb);  // qb = hn f32, hb = hn bf16
  gate_kernel<<<NTOK / 4, 256, 0, stream>>>(qb, gate_w, expert_bias, ti, tw, icnt, counts_out);
  scan_kernel<<<1, 64, 0, stream>>>(icnt, ebase);
  scatter_kernel<<<NTOK / 256, 256, 0, stream>>>(ti, ebase, cursor, tok2e);
  // MoE
  cvt_bf16_kernel<<<2048, 256, 0, stream>>>(w1, wxb, NEXP * DFF2 * DMODEL / 8);
  moe_mfma<0><<<dim3(DFF2 / 128, NTOK / 128, NEXP), 256, 0, stream>>>(hb, wxb, hmid, tok2e, ebase, icnt);
  cvt_bf16_kernel<<<2048, 256, 0, stream>>>(w2, wxb, NEXP * DMODEL * DFF2 / 8);
  moe_mfma<1><<<dim3(DMODEL / 128, NTOK / 128, NEXP), 256, 0, stream>>>(hmid, wxb, yb, tok2e, ebase, icnt);
  combine_kernel<<<NTOK, 256, 0, stream>>>(h, yb, tw, out);
}